// Round 2
// baseline (320.134 us; speedup 1.0000x reference)
//
#include <hip/hip_runtime.h>

// MHA forward: B=2, S=2048, D=1024, H=16, DK=64. fp32 in/out, bf16 MFMA compute.
// R2 = R1 resubmit (container infra failure, no signal). Correctness-first:
// 64x64 bf16 MFMA GEMM (fused f32->bf16 staging), flash attention
// (64 q-rows/block, KV tiles of 64, online softmax).

#define S_LEN 2048
#define NHEAD 16
#define DMODEL 1024
#define DKH 64
#define LDT 88   // padded LDS row stride (bf16 elems): 176 B, 16B-aligned, 2-way banks

typedef unsigned short u16;
typedef __attribute__((ext_vector_type(8))) short short8;
typedef __attribute__((ext_vector_type(8))) __bf16 bf16x8;
typedef __attribute__((ext_vector_type(4))) float f32x4;

__device__ inline u16 f2bf(float f) {
  unsigned u = __builtin_bit_cast(unsigned, f);
  u += 0x7fffu + ((u >> 16) & 1u);          // RNE
  return (u16)(u >> 16);
}
__device__ inline __bf16 bfbits(u16 x) { return __builtin_bit_cast(__bf16, x); }

__device__ inline f32x4 mfma16x16(bf16x8 a, bf16x8 b, f32x4 c) {
  return __builtin_amdgcn_mfma_f32_16x16x32_bf16(a, b, c, 0, 0, 0);
}

__device__ inline short8 pack8(float4 a, float4 b) {
  short8 r;
  r[0] = (short)f2bf(a.x); r[1] = (short)f2bf(a.y);
  r[2] = (short)f2bf(a.z); r[3] = (short)f2bf(a.w);
  r[4] = (short)f2bf(b.x); r[5] = (short)f2bf(b.y);
  r[6] = (short)f2bf(b.z); r[7] = (short)f2bf(b.w);
  return r;
}

// C[M,N] = A[M,K] @ Bt[N,K]^T + bias. A: f32 (AF32) or bf16. Bt: f32 (weights).
// HEAD: write bf16 into [b][h][s][dk] head-split layout; else f32 row-major.
template<bool AF32, bool HEAD>
__global__ __launch_bounds__(256)
void gemm64(const void* __restrict__ Ap, const float* __restrict__ Bt,
            const float* __restrict__ bias, void* __restrict__ outp,
            int M, int N, int K)
{
  __shared__ u16 As[64 * LDT];
  __shared__ u16 Bs[64 * LDT];
  const int t = threadIdx.x;
  const int lane = t & 63;
  const int wv = t >> 6;
  const int wm = wv >> 1, wn = wv & 1;      // 2x2 wave grid, 32x32 per wave
  const int g = lane >> 4, lr = lane & 15;
  const int bm = blockIdx.y << 6, bn = blockIdx.x << 6;

  f32x4 acc[2][2] = {};
  const int nk = K >> 6;
  for (int kt = 0; kt < nk; ++kt) {
    const int k0 = kt << 6;
    __syncthreads();
#pragma unroll
    for (int i = 0; i < 2; ++i) {
      int c = t + (i << 8);                 // 0..511 chunks of 8 elems
      int row = c >> 3, col = (c & 7) << 3;
      short8 av;
      if (AF32) {
        const float* Af = (const float*)Ap;
        const float4* pa = (const float4*)&Af[(size_t)(bm + row) * K + k0 + col];
        av = pack8(pa[0], pa[1]);
      } else {
        av = *(const short8*)&((const u16*)Ap)[(size_t)(bm + row) * K + k0 + col];
      }
      *(short8*)&As[row * LDT + col] = av;
      const float4* pb = (const float4*)&Bt[(size_t)(bn + row) * K + k0 + col];
      *(short8*)&Bs[row * LDT + col] = pack8(pb[0], pb[1]);
    }
    __syncthreads();
    bf16x8 af[2][2], bfr[2][2];
#pragma unroll
    for (int kc = 0; kc < 2; ++kc) {
#pragma unroll
      for (int fm = 0; fm < 2; ++fm)
        af[kc][fm] = *(const bf16x8*)&As[(wm * 32 + fm * 16 + lr) * LDT + kc * 32 + g * 8];
#pragma unroll
      for (int fn = 0; fn < 2; ++fn)
        bfr[kc][fn] = *(const bf16x8*)&Bs[(wn * 32 + fn * 16 + lr) * LDT + kc * 32 + g * 8];
    }
#pragma unroll
    for (int kc = 0; kc < 2; ++kc)
#pragma unroll
      for (int fm = 0; fm < 2; ++fm)
#pragma unroll
        for (int fn = 0; fn < 2; ++fn)
          acc[fm][fn] = mfma16x16(af[kc][fm], bfr[kc][fn], acc[fm][fn]);
  }
  // epilogue: D row = 4*(l>>4)+r, col = l&15 (m89-verified)
#pragma unroll
  for (int fm = 0; fm < 2; ++fm)
#pragma unroll
    for (int fn = 0; fn < 2; ++fn) {
      const int col = bn + wn * 32 + fn * 16 + lr;
      const float bb = bias[col];
#pragma unroll
      for (int r = 0; r < 4; ++r) {
        const int row = bm + wm * 32 + fm * 16 + g * 4 + r;
        float vv = acc[fm][fn][r] + bb;
        if (HEAD) {
          int b = row >> 11, s = row & (S_LEN - 1);
          int h = col >> 6, dk = col & (DKH - 1);
          ((u16*)outp)[(((size_t)(b * NHEAD + h)) * S_LEN + s) * DKH + dk] = f2bf(vv);
        } else {
          ((float*)outp)[(size_t)row * N + col] = vv;
        }
      }
    }
}

// Flash attention, causal. One block = 64 q rows (4 waves x 16), KV tiles of 64.
__global__ __launch_bounds__(256)
void attn_fwd(const u16* __restrict__ Qh, const u16* __restrict__ Kh,
              const u16* __restrict__ Vh, u16* __restrict__ Ao)
{
  __shared__ u16 Ks[64 * LDT];
  __shared__ u16 Vs[64 * LDT];
  __shared__ u16 Ps[4][16 * LDT];
  const int t = threadIdx.x, lane = t & 63, w = t >> 6;
  const int g = lane >> 4, lr = lane & 15;
  const int bh = blockIdx.y;                 // b*16 + h
  const int qb = blockIdx.x << 6;
  const u16* Qb = Qh + (size_t)bh * S_LEN * DKH;
  const u16* Kb = Kh + (size_t)bh * S_LEN * DKH;
  const u16* Vb = Vh + (size_t)bh * S_LEN * DKH;

  // Q fragments live in regs for the whole block (A-operand: row=lr, k=8g+i)
  bf16x8 qf[2];
#pragma unroll
  for (int kc = 0; kc < 2; ++kc)
    qf[kc] = *(const bf16x8*)&Qb[(size_t)(qb + w * 16 + lr) * DKH + kc * 32 + g * 8];

  f32x4 o[4] = {};
  float m[4], l[4];
#pragma unroll
  for (int r = 0; r < 4; ++r) { m[r] = -1e30f; l[r] = 0.f; }

  const int ntiles = blockIdx.x + 1;         // causal: kv tiles 0..qb/64
  for (int kt = 0; kt < ntiles; ++kt) {
    const int kv0 = kt << 6;
    __syncthreads();
#pragma unroll
    for (int i = 0; i < 2; ++i) {
      int c = t + (i << 8);
      int row = c >> 3, col = (c & 7) << 3;
      *(short8*)&Ks[row * LDT + col] = *(const short8*)&Kb[(size_t)(kv0 + row) * DKH + col];
      *(short8*)&Vs[row * LDT + col] = *(const short8*)&Vb[(size_t)(kv0 + row) * DKH + col];
    }
    __syncthreads();
    // S = (Q K^T) / 8 : 4 column-frags of 16
    f32x4 sf[4];
#pragma unroll
    for (int fk = 0; fk < 4; ++fk) {
      f32x4 a = {};
#pragma unroll
      for (int kc = 0; kc < 2; ++kc) {
        bf16x8 kf = *(const bf16x8*)&Ks[(fk * 16 + lr) * LDT + kc * 32 + g * 8];
        a = mfma16x16(qf[kc], kf, a);
      }
      sf[fk] = a;
    }
#pragma unroll
    for (int fk = 0; fk < 4; ++fk)
#pragma unroll
      for (int r = 0; r < 4; ++r)
        sf[fk][r] *= 0.125f;
    if (kt == ntiles - 1) {                  // only diagonal tile needs the mask
#pragma unroll
      for (int fk = 0; fk < 4; ++fk) {
        const int kv = kv0 + fk * 16 + lr;
#pragma unroll
        for (int r = 0; r < 4; ++r) {
          const int qq = qb + w * 16 + g * 4 + r;
          if (kv > qq) sf[fk][r] = -1e30f;
        }
      }
    }
    // online softmax: rows are 4g+r, cols spread over 16 lanes
    float p[4][4];
#pragma unroll
    for (int r = 0; r < 4; ++r) {
      float x = fmaxf(fmaxf(sf[0][r], sf[1][r]), fmaxf(sf[2][r], sf[3][r]));
#pragma unroll
      for (int off = 1; off < 16; off <<= 1)
        x = fmaxf(x, __shfl_xor(x, off));
      const float mn = fmaxf(m[r], x);
      const float alpha = __expf(m[r] - mn);
      m[r] = mn;
      float rs = 0.f;
#pragma unroll
      for (int fk = 0; fk < 4; ++fk) {
        float pv = __expf(sf[fk][r] - mn);
        p[fk][r] = pv;
        rs += pv;
      }
#pragma unroll
      for (int off = 1; off < 16; off <<= 1)
        rs += __shfl_xor(rs, off);
      l[r] = l[r] * alpha + rs;
#pragma unroll
      for (int d = 0; d < 4; ++d) o[d][r] *= alpha;
    }
    // P -> LDS (acc layout) so it can be re-read in A-operand layout
#pragma unroll
    for (int fk = 0; fk < 4; ++fk)
#pragma unroll
      for (int r = 0; r < 4; ++r)
        Ps[w][(g * 4 + r) * LDT + fk * 16 + lr] = f2bf(p[fk][r]);
    __syncthreads();
    // O += P V
#pragma unroll
    for (int kc = 0; kc < 2; ++kc) {
      bf16x8 pf = *(const bf16x8*)&Ps[w][lr * LDT + kc * 32 + g * 8];
#pragma unroll
      for (int df = 0; df < 4; ++df) {
        bf16x8 vf;
#pragma unroll
        for (int i = 0; i < 8; ++i)
          vf[i] = bfbits(Vs[(kc * 32 + g * 8 + i) * LDT + df * 16 + lr]);
        o[df] = mfma16x16(pf, vf, o[df]);
      }
    }
  }
  // write attention output in (B,S,D) layout, bf16, for the final projection
  const int b = bh >> 4, h = bh & (NHEAD - 1);
#pragma unroll
  for (int df = 0; df < 4; ++df)
#pragma unroll
    for (int r = 0; r < 4; ++r) {
      const int qq = qb + w * 16 + g * 4 + r;
      const int d = df * 16 + lr;
      Ao[((size_t)(b * S_LEN + qq)) * DMODEL + h * DKH + d] = f2bf(o[df][r] / l[r]);
    }
}

extern "C" void kernel_launch(void* const* d_in, const int* in_sizes, int n_in,
                              void* d_out, int out_size, void* d_ws, size_t ws_size,
                              hipStream_t stream)
{
  (void)in_sizes; (void)n_in; (void)out_size; (void)ws_size;
  const float* q  = (const float*)d_in[0];
  const float* k  = (const float*)d_in[1];
  const float* v  = (const float*)d_in[2];
  // d_in[3] = mask (tril, causal) — implemented analytically
  const float* Wq = (const float*)d_in[4];
  const float* bq = (const float*)d_in[5];
  const float* Wk = (const float*)d_in[6];
  const float* bk = (const float*)d_in[7];
  const float* Wv = (const float*)d_in[8];
  const float* bv = (const float*)d_in[9];
  const float* Wo = (const float*)d_in[10];
  const float* bo = (const float*)d_in[11];

  char* ws = (char*)d_ws;
  u16* Qh = (u16*)(ws);                                  // 8 MB  [b][h][s][dk] bf16
  u16* Kh = (u16*)(ws + (size_t)8 * 1024 * 1024);        // 8 MB
  u16* Vh = (u16*)(ws + (size_t)16 * 1024 * 1024);       // 8 MB
  u16* Ao = (u16*)(ws + (size_t)24 * 1024 * 1024);       // 8 MB  [b][s][h*dk] bf16

  const int M = 2 * S_LEN, N = DMODEL, K = DMODEL;
  dim3 gg(N / 64, M / 64), bb(256);
  gemm64<true, true><<<gg, bb, 0, stream>>>(q, Wq, bq, Qh, M, N, K);
  gemm64<true, true><<<gg, bb, 0, stream>>>(k, Wk, bk, Kh, M, N, K);
  gemm64<true, true><<<gg, bb, 0, stream>>>(v, Wv, bv, Vh, M, N, K);
  attn_fwd<<<dim3(S_LEN / 64, 2 * NHEAD), bb, 0, stream>>>(Qh, Kh, Vh, Ao);
  gemm64<false, false><<<gg, bb, 0, stream>>>(Ao, Wo, bo, d_out, M, N, K);
}

// Round 4
// 201.456 us; speedup vs baseline: 1.5891x; 1.5891x over previous
//
#include <hip/hip_runtime.h>

// MHA forward: B=2, S=2048, D=1024, H=16, DK=64. fp32 in/out, bf16 MFMA compute.
// R4 = R3 resubmit (container infra failure, no signal). Attention restructure:
//  - causal pairing: block owns q-tiles {p, 31-p} -> uniform work, 2 blocks/CU
//  - V written TRANSPOSED [bh][dk][s] by the V-projection GEMM -> PV B-frags
//    are contiguous ds_read_b128 (was 64 scalar u16 reads w/ 4-way conflicts)
//  - double-buffered K/V staging (loads issued one tile early), 1 barrier/tile

#define S_LEN 2048
#define NHEAD 16
#define DMODEL 1024
#define DKH 64
#define LDT 88   // padded LDS row stride (bf16 elems): 176 B, 16B-aligned

typedef unsigned short u16;
typedef __attribute__((ext_vector_type(8))) short short8;
typedef __attribute__((ext_vector_type(8))) __bf16 bf16x8;
typedef __attribute__((ext_vector_type(4))) float f32x4;

__device__ inline u16 f2bf(float f) {
  unsigned u = __builtin_bit_cast(unsigned, f);
  u += 0x7fffu + ((u >> 16) & 1u);          // RNE
  return (u16)(u >> 16);
}

__device__ inline f32x4 mfma16x16(bf16x8 a, bf16x8 b, f32x4 c) {
  return __builtin_amdgcn_mfma_f32_16x16x32_bf16(a, b, c, 0, 0, 0);
}

__device__ inline short8 pack8(float4 a, float4 b) {
  short8 r;
  r[0] = (short)f2bf(a.x); r[1] = (short)f2bf(a.y);
  r[2] = (short)f2bf(a.z); r[3] = (short)f2bf(a.w);
  r[4] = (short)f2bf(b.x); r[5] = (short)f2bf(b.y);
  r[6] = (short)f2bf(b.z); r[7] = (short)f2bf(b.w);
  return r;
}

// C[M,N] = A[M,K] @ Bt[N,K]^T + bias.
// AF32: A is f32 (convert during staging) else bf16.
// OMODE 0: f32 row-major out. 1: bf16 head-split [b][h][s][dk].
//       2: bf16 TRANSPOSED head-split [b][h][dk][s] (for V).
template<bool AF32, int OMODE>
__global__ __launch_bounds__(256)
void gemm64(const void* __restrict__ Ap, const float* __restrict__ Bt,
            const float* __restrict__ bias, void* __restrict__ outp,
            int M, int N, int K)
{
  __shared__ u16 As[64 * LDT];
  __shared__ u16 Bs[64 * LDT];
  const int t = threadIdx.x;
  const int lane = t & 63;
  const int wv = t >> 6;
  const int wm = wv >> 1, wn = wv & 1;      // 2x2 wave grid, 32x32 per wave
  const int g = lane >> 4, lr = lane & 15;
  const int bm = blockIdx.y << 6, bn = blockIdx.x << 6;

  f32x4 acc[2][2] = {};
  const int nk = K >> 6;
  for (int kt = 0; kt < nk; ++kt) {
    const int k0 = kt << 6;
    __syncthreads();
#pragma unroll
    for (int i = 0; i < 2; ++i) {
      int c = t + (i << 8);
      int row = c >> 3, col = (c & 7) << 3;
      short8 av;
      if (AF32) {
        const float* Af = (const float*)Ap;
        const float4* pa = (const float4*)&Af[(size_t)(bm + row) * K + k0 + col];
        av = pack8(pa[0], pa[1]);
      } else {
        av = *(const short8*)&((const u16*)Ap)[(size_t)(bm + row) * K + k0 + col];
      }
      *(short8*)&As[row * LDT + col] = av;
      const float4* pb = (const float4*)&Bt[(size_t)(bn + row) * K + k0 + col];
      *(short8*)&Bs[row * LDT + col] = pack8(pb[0], pb[1]);
    }
    __syncthreads();
    bf16x8 af[2][2], bfr[2][2];
#pragma unroll
    for (int kc = 0; kc < 2; ++kc) {
#pragma unroll
      for (int fm = 0; fm < 2; ++fm)
        af[kc][fm] = *(const bf16x8*)&As[(wm * 32 + fm * 16 + lr) * LDT + kc * 32 + g * 8];
#pragma unroll
      for (int fn = 0; fn < 2; ++fn)
        bfr[kc][fn] = *(const bf16x8*)&Bs[(wn * 32 + fn * 16 + lr) * LDT + kc * 32 + g * 8];
    }
#pragma unroll
    for (int kc = 0; kc < 2; ++kc)
#pragma unroll
      for (int fm = 0; fm < 2; ++fm)
#pragma unroll
        for (int fn = 0; fn < 2; ++fn)
          acc[fm][fn] = mfma16x16(af[kc][fm], bfr[kc][fn], acc[fm][fn]);
  }
  // epilogue: D row = 4*(l>>4)+r, col = l&15 (m89-verified)
  if (OMODE == 2) {
    // transpose via LDS (reuse As), then coalesced bf16 stores to [bh][dk][s]
    u16* TL = As;
    __syncthreads();
#pragma unroll
    for (int fm = 0; fm < 2; ++fm)
#pragma unroll
      for (int fn = 0; fn < 2; ++fn) {
        const int lc = wn * 32 + fn * 16 + lr;       // local col = dk
        const float bb = bias[bn + lc];
#pragma unroll
        for (int r = 0; r < 4; ++r) {
          const int lrow = wm * 32 + fm * 16 + g * 4 + r;   // local row = s
          TL[lc * LDT + lrow] = f2bf(acc[fm][fn][r] + bb);
        }
      }
    __syncthreads();
    const int bh = (bm >> 11) * NHEAD + (bn >> 6);
    const int s0 = bm & (S_LEN - 1);
#pragma unroll
    for (int i = 0; i < 2; ++i) {
      int c = t + (i << 8);
      int dr = c >> 3, sc = (c & 7) << 3;
      short8 vv = *(const short8*)&TL[dr * LDT + sc];
      *(short8*)&((u16*)outp)[((size_t)bh * DKH + dr) * S_LEN + s0 + sc] = vv;
    }
  } else {
#pragma unroll
    for (int fm = 0; fm < 2; ++fm)
#pragma unroll
      for (int fn = 0; fn < 2; ++fn) {
        const int col = bn + wn * 32 + fn * 16 + lr;
        const float bb = bias[col];
#pragma unroll
        for (int r = 0; r < 4; ++r) {
          const int row = bm + wm * 32 + fm * 16 + g * 4 + r;
          float vv = acc[fm][fn][r] + bb;
          if (OMODE == 1) {
            int b = row >> 11, s = row & (S_LEN - 1);
            int h = col >> 6, dk = col & (DKH - 1);
            ((u16*)outp)[(((size_t)(b * NHEAD + h)) * S_LEN + s) * DKH + dk] = f2bf(vv);
          } else {
            ((float*)outp)[(size_t)row * N + col] = vv;
          }
        }
      }
  }
}

// Flash attention, causal, paired q-tiles {p, 31-p}. 4 waves x 16 q-rows per tile.
// K staged row-major [k][dk]; V staged from transposed global [dk][k].
__global__ __launch_bounds__(256)
void attn_fwd(const u16* __restrict__ Qh, const u16* __restrict__ Kh,
              const u16* __restrict__ Vtg, u16* __restrict__ Ao)
{
  __shared__ u16 Ks[2][64 * LDT];
  __shared__ u16 Vs[2][64 * LDT];   // V^T tile: row=dk, col=k
  __shared__ u16 Ps[8][16 * LDT];   // per-wave P buffers, separate A/B slots
  const int t = threadIdx.x, lane = t & 63, w = t >> 6;
  const int g = lane >> 4, lr = lane & 15;
  const int bh = blockIdx.y;
  const int pA = blockIdx.x;                 // 0..15
  const int tA = pA, tB = 31 - pA;
  const u16* Qb = Qh + (size_t)bh * S_LEN * DKH;
  const u16* Kb = Kh + (size_t)bh * S_LEN * DKH;
  const u16* Vb = Vtg + (size_t)bh * DKH * S_LEN;

  bf16x8 qfA[2], qfB[2];
#pragma unroll
  for (int kc = 0; kc < 2; ++kc) {
    qfA[kc] = *(const bf16x8*)&Qb[(size_t)(tA * 64 + w * 16 + lr) * DKH + kc * 32 + g * 8];
    qfB[kc] = *(const bf16x8*)&Qb[(size_t)(tB * 64 + w * 16 + lr) * DKH + kc * 32 + g * 8];
  }

  f32x4 oA[4] = {}, oB[4] = {};
  float mA[4], lA[4], mB[4], lB[4];
#pragma unroll
  for (int r = 0; r < 4; ++r) { mA[r] = mB[r] = -1e30f; lA[r] = lB[r] = 0.f; }

  const int r0 = t >> 3;            // 0..31
  const int c0 = (t & 7) << 3;      // 0..56
  short8 kr0, kr1, vr0, vr1;

  auto LOADT = [&](int kt) {
    const int kv0 = kt << 6;
    kr0 = *(const short8*)&Kb[(size_t)(kv0 + r0) * DKH + c0];
    kr1 = *(const short8*)&Kb[(size_t)(kv0 + r0 + 32) * DKH + c0];
    vr0 = *(const short8*)&Vb[(size_t)r0 * S_LEN + kv0 + c0];
    vr1 = *(const short8*)&Vb[(size_t)(r0 + 32) * S_LEN + kv0 + c0];
  };
  auto WRITET = [&](int b) {
    *(short8*)&Ks[b][r0 * LDT + c0] = kr0;
    *(short8*)&Ks[b][(r0 + 32) * LDT + c0] = kr1;
    *(short8*)&Vs[b][r0 * LDT + c0] = vr0;
    *(short8*)&Vs[b][(r0 + 32) * LDT + c0] = vr1;
  };

  auto COMPUTE = [&](int buf, const bf16x8* qf, f32x4* o, float* m, float* l,
                     int pslot, bool diag) {
    f32x4 sf[4];
#pragma unroll
    for (int fk = 0; fk < 4; ++fk) {
      f32x4 a = {};
#pragma unroll
      for (int kc = 0; kc < 2; ++kc) {
        bf16x8 kf = *(const bf16x8*)&Ks[buf][(fk * 16 + lr) * LDT + kc * 32 + g * 8];
        a = mfma16x16(qf[kc], kf, a);
      }
      sf[fk] = a;
    }
#pragma unroll
    for (int fk = 0; fk < 4; ++fk)
#pragma unroll
      for (int r = 0; r < 4; ++r)
        sf[fk][r] *= 0.125f;
    if (diag) {
#pragma unroll
      for (int fk = 0; fk < 4; ++fk) {
        const int kvl = fk * 16 + lr;
#pragma unroll
        for (int r = 0; r < 4; ++r)
          if (kvl > w * 16 + g * 4 + r) sf[fk][r] = -1e30f;
      }
    }
    float p[4][4];
#pragma unroll
    for (int r = 0; r < 4; ++r) {
      float x = fmaxf(fmaxf(sf[0][r], sf[1][r]), fmaxf(sf[2][r], sf[3][r]));
#pragma unroll
      for (int off = 1; off < 16; off <<= 1)
        x = fmaxf(x, __shfl_xor(x, off));
      const float mn = fmaxf(m[r], x);
      const float alpha = __expf(m[r] - mn);
      m[r] = mn;
      float rs = 0.f;
#pragma unroll
      for (int fk = 0; fk < 4; ++fk) {
        float pv = __expf(sf[fk][r] - mn);
        p[fk][r] = pv;
        rs += pv;
      }
#pragma unroll
      for (int off = 1; off < 16; off <<= 1)
        rs += __shfl_xor(rs, off);
      l[r] = l[r] * alpha + rs;
#pragma unroll
      for (int d = 0; d < 4; ++d) o[d][r] *= alpha;
    }
    // P (acc layout) -> per-wave LDS -> re-read as A-fragment. No barrier:
    // same-wave LDS RAW, compiler inserts lgkmcnt.
#pragma unroll
    for (int fk = 0; fk < 4; ++fk)
#pragma unroll
      for (int r = 0; r < 4; ++r)
        Ps[pslot][(g * 4 + r) * LDT + fk * 16 + lr] = f2bf(p[fk][r]);
#pragma unroll
    for (int kc = 0; kc < 2; ++kc) {
      bf16x8 pf = *(const bf16x8*)&Ps[pslot][lr * LDT + kc * 32 + g * 8];
#pragma unroll
      for (int df = 0; df < 4; ++df) {
        bf16x8 vf = *(const bf16x8*)&Vs[buf][(df * 16 + lr) * LDT + kc * 32 + g * 8];
        o[df] = mfma16x16(pf, vf, o[df]);
      }
    }
  };

  const int nt = tB + 1;
  LOADT(0);
  WRITET(0);
  for (int kt = 0; kt < nt; ++kt) {
    const int cur = kt & 1;
    const bool more = (kt + 1 < nt);
    if (more) LOADT(kt + 1);         // global loads in flight during compute
    __syncthreads();                 // buf[cur] writes visible to all waves
    if (kt <= tA) COMPUTE(cur, qfA, oA, mA, lA, w, kt == tA);
    COMPUTE(cur, qfB, oB, mB, lB, 4 + w, kt == tB);
    if (more) WRITET(cur ^ 1);       // safe: everyone passed this iter's barrier
  }

  const int b = bh >> 4, h = bh & (NHEAD - 1);
#pragma unroll
  for (int df = 0; df < 4; ++df)
#pragma unroll
    for (int r = 0; r < 4; ++r) {
      const int d = df * 16 + lr;
      const int qa = tA * 64 + w * 16 + g * 4 + r;
      const int qb2 = tB * 64 + w * 16 + g * 4 + r;
      Ao[((size_t)(b * S_LEN + qa)) * DMODEL + h * DKH + d] = f2bf(oA[df][r] / lA[r]);
      Ao[((size_t)(b * S_LEN + qb2)) * DMODEL + h * DKH + d] = f2bf(oB[df][r] / lB[r]);
    }
}

extern "C" void kernel_launch(void* const* d_in, const int* in_sizes, int n_in,
                              void* d_out, int out_size, void* d_ws, size_t ws_size,
                              hipStream_t stream)
{
  (void)in_sizes; (void)n_in; (void)out_size; (void)ws_size;
  const float* q  = (const float*)d_in[0];
  const float* k  = (const float*)d_in[1];
  const float* v  = (const float*)d_in[2];
  // d_in[3] = mask (tril, causal) — implemented analytically
  const float* Wq = (const float*)d_in[4];
  const float* bq = (const float*)d_in[5];
  const float* Wk = (const float*)d_in[6];
  const float* bk = (const float*)d_in[7];
  const float* Wv = (const float*)d_in[8];
  const float* bv = (const float*)d_in[9];
  const float* Wo = (const float*)d_in[10];
  const float* bo = (const float*)d_in[11];

  char* ws = (char*)d_ws;
  u16* Qh = (u16*)(ws);                                  // 8 MB [b][h][s][dk]
  u16* Kh = (u16*)(ws + (size_t)8 * 1024 * 1024);        // 8 MB [b][h][s][dk]
  u16* Vt = (u16*)(ws + (size_t)16 * 1024 * 1024);       // 8 MB [b][h][dk][s]
  u16* Ao = (u16*)(ws + (size_t)24 * 1024 * 1024);       // 8 MB [b][s][h*dk]

  const int M = 2 * S_LEN, N = DMODEL, K = DMODEL;
  dim3 gg(N / 64, M / 64), bb(256);
  gemm64<true, 1><<<gg, bb, 0, stream>>>(q, Wq, bq, Qh, M, N, K);
  gemm64<true, 1><<<gg, bb, 0, stream>>>(k, Wk, bk, Kh, M, N, K);
  gemm64<true, 2><<<gg, bb, 0, stream>>>(v, Wv, bv, Vt, M, N, K);
  attn_fwd<<<dim3(16, 2 * NHEAD), bb, 0, stream>>>(Qh, Kh, Vt, Ao);
  gemm64<false, 0><<<gg, bb, 0, stream>>>(Ao, Wo, bo, d_out, M, N, K);
}

// Round 5
// 181.395 us; speedup vs baseline: 1.7648x; 1.1106x over previous
//
#include <hip/hip_runtime.h>

// MHA forward: B=2, S=2048, D=1024, H=16, DK=64. fp32 in/out, bf16 MFMA compute.
// R5: GEMM overhaul (attention unchanged from R4).
//  - weights pre-converted to bf16 (one dispatch) -> B staged via global_load_lds w=16
//  - 3 projection GEMMs batched in one dispatch (grid.z), 128x128 tile, BK=64,
//    4 waves x (64x64) acc; A fp32 reg-staged w/ hw cvt; V written transposed
//  - O-GEMM: both operands global_load_lds; A read from head-split Ao by
//    per-lane permuted source address
//  - ws needs 40 MB; runtime fallback to R4 path if ws_size < 40 MB

#define S_LEN 2048
#define NHEAD 16
#define DMODEL 1024
#define DKH 64
#define LDT 88   // padded LDS row stride for 64-wide tiles (old path + attn)

typedef unsigned short u16;
typedef __attribute__((ext_vector_type(8))) short short8;
typedef __attribute__((ext_vector_type(8))) __bf16 bf16x8;
typedef __attribute__((ext_vector_type(4))) float f32x4;

__device__ inline u16 f2bf(float f) {
  return __builtin_bit_cast(u16, (__bf16)f);   // v_cvt RNE
}

__device__ inline f32x4 mfma16x16(bf16x8 a, bf16x8 b, f32x4 c) {
  return __builtin_amdgcn_mfma_f32_16x16x32_bf16(a, b, c, 0, 0, 0);
}

__device__ inline short8 pack8(float4 a, float4 b) {
  short8 r;
  r[0] = (short)f2bf(a.x); r[1] = (short)f2bf(a.y);
  r[2] = (short)f2bf(a.z); r[3] = (short)f2bf(a.w);
  r[4] = (short)f2bf(b.x); r[5] = (short)f2bf(b.y);
  r[6] = (short)f2bf(b.z); r[7] = (short)f2bf(b.w);
  return r;
}

typedef const __attribute__((address_space(1))) unsigned GU32;
typedef __attribute__((address_space(3))) unsigned LU32;
__device__ inline void gl2lds16(const void* g, void* l) {
  __builtin_amdgcn_global_load_lds((GU32*)g, (LU32*)l, 16, 0, 0);
}

// ---------- weight conversion: 4x [1024x1024] f32 -> bf16 ----------
__global__ __launch_bounds__(256)
void conv_w(const float* __restrict__ w0, const float* __restrict__ w1,
            const float* __restrict__ w2, const float* __restrict__ w3,
            u16* __restrict__ o0, u16* __restrict__ o1,
            u16* __restrict__ o2, u16* __restrict__ o3)
{
  const int z = blockIdx.y;
  const float* s = z == 0 ? w0 : z == 1 ? w1 : z == 2 ? w2 : w3;
  u16* d = z == 0 ? o0 : z == 1 ? o1 : z == 2 ? o2 : o3;
  const int i = (blockIdx.x * 256 + threadIdx.x) * 8;
  float4 a = *(const float4*)&s[i];
  float4 b = *(const float4*)&s[i + 4];
  *(short8*)&d[i] = pack8(a, b);
}

// ---------- batched projection GEMMs (q,k,v) x (Wq,Wk,Wv), 128x128, BK=64 ----
// z=0,1 -> bf16 head-split [bh][s][dk]; z=2 -> bf16 transposed [bh][dk][s]
__global__ __launch_bounds__(256)
void proj_gemm(const float* __restrict__ Aq, const float* __restrict__ Akk,
               const float* __restrict__ Av,
               const u16* __restrict__ Bq, const u16* __restrict__ Bk,
               const u16* __restrict__ Bv,
               const float* __restrict__ cq, const float* __restrict__ ck,
               const float* __restrict__ cv,
               u16* __restrict__ Oq, u16* __restrict__ Ok, u16* __restrict__ Ov)
{
  __shared__ u16 SM[2 * 128 * 64];
  u16* As = SM;
  u16* Bs = SM + 128 * 64;
  const int zz = blockIdx.z;
  const float* Af = zz == 0 ? Aq : zz == 1 ? Akk : Av;
  const u16* Wb = zz == 0 ? Bq : zz == 1 ? Bk : Bv;
  const float* bias = zz == 0 ? cq : zz == 1 ? ck : cv;

  const int t = threadIdx.x;
  const int lane = t & 63;
  const int wv = t >> 6;
  const int wm = wv >> 1, wn = wv & 1;        // 2x2 waves, each 64x64
  const int g = lane >> 4, lr = lane & 15;
  const int bm = blockIdx.y << 7, bn = blockIdx.x << 7;
  const int K = DMODEL;

  f32x4 acc[4][4] = {};
  for (int kt = 0; kt < K / 64; ++kt) {
    const int k0 = kt << 6;
    __syncthreads();
    // B: bf16 weights via global_load_lds (LDS dest = uniform + lane*16)
#pragma unroll
    for (int i = 0; i < 4; ++i) {
      int c = t + (i << 8);
      int row = c >> 3, col = (c & 7) << 3;
      gl2lds16(&Wb[(size_t)(bn + row) * K + k0 + col], &Bs[c * 8]);
    }
    // A: fp32 -> bf16 reg-staged
#pragma unroll
    for (int i = 0; i < 4; ++i) {
      int c = t + (i << 8);
      int row = c >> 3, col = (c & 7) << 3;
      const float* src = &Af[(size_t)(bm + row) * K + k0 + col];
      float4 x = *(const float4*)src;
      float4 y = *(const float4*)(src + 4);
      *(short8*)&As[c * 8] = pack8(x, y);
    }
    __syncthreads();
    bf16x8 af[2][4], bf[2][4];
#pragma unroll
    for (int kc = 0; kc < 2; ++kc)
#pragma unroll
      for (int f = 0; f < 4; ++f) {
        af[kc][f] = *(const bf16x8*)&As[(wm * 64 + f * 16 + lr) * 64 + kc * 32 + g * 8];
        bf[kc][f] = *(const bf16x8*)&Bs[(wn * 64 + f * 16 + lr) * 64 + kc * 32 + g * 8];
      }
#pragma unroll
    for (int kc = 0; kc < 2; ++kc)
#pragma unroll
      for (int fm = 0; fm < 4; ++fm)
#pragma unroll
        for (int fn = 0; fn < 4; ++fn)
          acc[fm][fn] = mfma16x16(af[kc][fm], bf[kc][fn], acc[fm][fn]);
  }

  if (zz == 2) {
    // V: write transposed [bh][dk][s] via two-pass LDS transpose (tile spans 2 heads)
    u16* TL = SM;                              // 64 x 132 bf16 = 16.9 KB
    const int b = bm >> 11, s0 = bm & (S_LEN - 1), h0 = bn >> 6;
#pragma unroll
    for (int hh = 0; hh < 2; ++hh) {
      __syncthreads();
      if (wn == hh) {
#pragma unroll
        for (int fm = 0; fm < 4; ++fm)
#pragma unroll
          for (int fn = 0; fn < 4; ++fn) {
            const int lch = fn * 16 + lr;      // dk within head
            const float bb = bias[bn + hh * 64 + lch];
#pragma unroll
            for (int r = 0; r < 4; ++r)
              TL[lch * 132 + wm * 64 + fm * 16 + g * 4 + r] = f2bf(acc[fm][fn][r] + bb);
          }
      }
      __syncthreads();
#pragma unroll
      for (int i = 0; i < 4; ++i) {
        int c = t + (i << 8);
        int dk = c >> 4, sc = (c & 15) << 3;
        short8 vv = *(const short8*)&TL[dk * 132 + sc];
        *(short8*)&Ov[(((size_t)(b * NHEAD + h0 + hh)) * DKH + dk) * S_LEN + s0 + sc] = vv;
      }
    }
  } else {
    u16* Out = zz == 0 ? Oq : Ok;
#pragma unroll
    for (int fm = 0; fm < 4; ++fm)
#pragma unroll
      for (int fn = 0; fn < 4; ++fn) {
        const int col = bn + wn * 64 + fn * 16 + lr;
        const int h = col >> 6, dk = col & (DKH - 1);
        const float bb = bias[col];
#pragma unroll
        for (int r = 0; r < 4; ++r) {
          const int row = bm + wm * 64 + fm * 16 + g * 4 + r;
          const int b = row >> 11, s = row & (S_LEN - 1);
          Out[(((size_t)(b * NHEAD + h)) * S_LEN + s) * DKH + dk] = f2bf(acc[fm][fn][r] + bb);
        }
      }
  }
}

// ---------- O-projection: Ao(head-split bf16) @ Wo^T + bo -> f32 out ----------
__global__ __launch_bounds__(256)
void out_gemm(const u16* __restrict__ Ao, const u16* __restrict__ Wb,
              const float* __restrict__ bias, float* __restrict__ Out)
{
  __shared__ u16 SM[2 * 128 * 64];
  u16* As = SM;
  u16* Bs = SM + 128 * 64;
  const int t = threadIdx.x;
  const int lane = t & 63;
  const int wv = t >> 6;
  const int wm = wv >> 1, wn = wv & 1;
  const int g = lane >> 4, lr = lane & 15;
  const int bm = blockIdx.y << 7, bn = blockIdx.x << 7;
  const int K = DMODEL;

  f32x4 acc[4][4] = {};
  for (int kt = 0; kt < K / 64; ++kt) {
    const int k0 = kt << 6;
    __syncthreads();
#pragma unroll
    for (int i = 0; i < 4; ++i) {
      int c = t + (i << 8);
      int row = c >> 3, col = (c & 7) << 3;
      // A logical (row=b*2048+s, k=h*64+dk) lives at Ao[((b*16+h)*2048+s)*64+dk]
      int grow = bm + row;
      int b = grow >> 11, s = grow & (S_LEN - 1);
      int k = k0 + col;
      int h = k >> 6, dk = k & (DKH - 1);
      gl2lds16(&Ao[(((size_t)(b * NHEAD + h)) * S_LEN + s) * DKH + dk], &As[c * 8]);
      gl2lds16(&Wb[(size_t)(bn + row) * K + k0 + col], &Bs[c * 8]);
    }
    __syncthreads();
    bf16x8 af[2][4], bf[2][4];
#pragma unroll
    for (int kc = 0; kc < 2; ++kc)
#pragma unroll
      for (int f = 0; f < 4; ++f) {
        af[kc][f] = *(const bf16x8*)&As[(wm * 64 + f * 16 + lr) * 64 + kc * 32 + g * 8];
        bf[kc][f] = *(const bf16x8*)&Bs[(wn * 64 + f * 16 + lr) * 64 + kc * 32 + g * 8];
      }
#pragma unroll
    for (int kc = 0; kc < 2; ++kc)
#pragma unroll
      for (int fm = 0; fm < 4; ++fm)
#pragma unroll
        for (int fn = 0; fn < 4; ++fn)
          acc[fm][fn] = mfma16x16(af[kc][fm], bf[kc][fn], acc[fm][fn]);
  }
#pragma unroll
  for (int fm = 0; fm < 4; ++fm)
#pragma unroll
    for (int fn = 0; fn < 4; ++fn) {
      const int col = bn + wn * 64 + fn * 16 + lr;
      const float bb = bias[col];
#pragma unroll
      for (int r = 0; r < 4; ++r) {
        const int row = bm + wm * 64 + fm * 16 + g * 4 + r;
        Out[(size_t)row * DMODEL + col] = acc[fm][fn][r] + bb;
      }
    }
}

// ================= old R4 path (fallback if ws_size < 40 MB) =================
template<bool AF32, int OMODE>
__global__ __launch_bounds__(256)
void gemm64(const void* __restrict__ Ap, const float* __restrict__ Bt,
            const float* __restrict__ bias, void* __restrict__ outp,
            int M, int N, int K)
{
  __shared__ u16 As[64 * LDT];
  __shared__ u16 Bs[64 * LDT];
  const int t = threadIdx.x;
  const int lane = t & 63;
  const int wv = t >> 6;
  const int wm = wv >> 1, wn = wv & 1;
  const int g = lane >> 4, lr = lane & 15;
  const int bm = blockIdx.y << 6, bn = blockIdx.x << 6;

  f32x4 acc[2][2] = {};
  const int nk = K >> 6;
  for (int kt = 0; kt < nk; ++kt) {
    const int k0 = kt << 6;
    __syncthreads();
#pragma unroll
    for (int i = 0; i < 2; ++i) {
      int c = t + (i << 8);
      int row = c >> 3, col = (c & 7) << 3;
      short8 av;
      if (AF32) {
        const float* Af = (const float*)Ap;
        const float4* pa = (const float4*)&Af[(size_t)(bm + row) * K + k0 + col];
        av = pack8(pa[0], pa[1]);
      } else {
        av = *(const short8*)&((const u16*)Ap)[(size_t)(bm + row) * K + k0 + col];
      }
      *(short8*)&As[row * LDT + col] = av;
      const float4* pb = (const float4*)&Bt[(size_t)(bn + row) * K + k0 + col];
      *(short8*)&Bs[row * LDT + col] = pack8(pb[0], pb[1]);
    }
    __syncthreads();
    bf16x8 af[2][2], bfr[2][2];
#pragma unroll
    for (int kc = 0; kc < 2; ++kc) {
#pragma unroll
      for (int fm = 0; fm < 2; ++fm)
        af[kc][fm] = *(const bf16x8*)&As[(wm * 32 + fm * 16 + lr) * LDT + kc * 32 + g * 8];
#pragma unroll
      for (int fn = 0; fn < 2; ++fn)
        bfr[kc][fn] = *(const bf16x8*)&Bs[(wn * 32 + fn * 16 + lr) * LDT + kc * 32 + g * 8];
    }
#pragma unroll
    for (int kc = 0; kc < 2; ++kc)
#pragma unroll
      for (int fm = 0; fm < 2; ++fm)
#pragma unroll
        for (int fn = 0; fn < 2; ++fn)
          acc[fm][fn] = mfma16x16(af[kc][fm], bfr[kc][fn], acc[fm][fn]);
  }
  if (OMODE == 2) {
    u16* TL = As;
    __syncthreads();
#pragma unroll
    for (int fm = 0; fm < 2; ++fm)
#pragma unroll
      for (int fn = 0; fn < 2; ++fn) {
        const int lc = wn * 32 + fn * 16 + lr;
        const float bb = bias[bn + lc];
#pragma unroll
        for (int r = 0; r < 4; ++r) {
          const int lrow = wm * 32 + fm * 16 + g * 4 + r;
          TL[lc * LDT + lrow] = f2bf(acc[fm][fn][r] + bb);
        }
      }
    __syncthreads();
    const int bh = (bm >> 11) * NHEAD + (bn >> 6);
    const int s0 = bm & (S_LEN - 1);
#pragma unroll
    for (int i = 0; i < 2; ++i) {
      int c = t + (i << 8);
      int dr = c >> 3, sc = (c & 7) << 3;
      short8 vv = *(const short8*)&TL[dr * LDT + sc];
      *(short8*)&((u16*)outp)[((size_t)bh * DKH + dr) * S_LEN + s0 + sc] = vv;
    }
  } else {
#pragma unroll
    for (int fm = 0; fm < 2; ++fm)
#pragma unroll
      for (int fn = 0; fn < 2; ++fn) {
        const int col = bn + wn * 32 + fn * 16 + lr;
        const float bb = bias[col];
#pragma unroll
        for (int r = 0; r < 4; ++r) {
          const int row = bm + wm * 32 + fm * 16 + g * 4 + r;
          float vv = acc[fm][fn][r] + bb;
          if (OMODE == 1) {
            int b = row >> 11, s = row & (S_LEN - 1);
            int h = col >> 6, dk = col & (DKH - 1);
            ((u16*)outp)[(((size_t)(b * NHEAD + h)) * S_LEN + s) * DKH + dk] = f2bf(vv);
          } else {
            ((float*)outp)[(size_t)row * N + col] = vv;
          }
        }
      }
  }
}

// Flash attention, causal, paired q-tiles {p, 31-p}. HS: Ao head-split layout.
template<bool HS>
__global__ __launch_bounds__(256)
void attn_fwd(const u16* __restrict__ Qh, const u16* __restrict__ Kh,
              const u16* __restrict__ Vtg, u16* __restrict__ Ao)
{
  __shared__ u16 Ks[2][64 * LDT];
  __shared__ u16 Vs[2][64 * LDT];
  __shared__ u16 Ps[8][16 * LDT];
  const int t = threadIdx.x, lane = t & 63, w = t >> 6;
  const int g = lane >> 4, lr = lane & 15;
  const int bh = blockIdx.y;
  const int pA = blockIdx.x;
  const int tA = pA, tB = 31 - pA;
  const u16* Qb = Qh + (size_t)bh * S_LEN * DKH;
  const u16* Kb = Kh + (size_t)bh * S_LEN * DKH;
  const u16* Vb = Vtg + (size_t)bh * DKH * S_LEN;

  bf16x8 qfA[2], qfB[2];
#pragma unroll
  for (int kc = 0; kc < 2; ++kc) {
    qfA[kc] = *(const bf16x8*)&Qb[(size_t)(tA * 64 + w * 16 + lr) * DKH + kc * 32 + g * 8];
    qfB[kc] = *(const bf16x8*)&Qb[(size_t)(tB * 64 + w * 16 + lr) * DKH + kc * 32 + g * 8];
  }

  f32x4 oA[4] = {}, oB[4] = {};
  float mA[4], lA[4], mB[4], lB[4];
#pragma unroll
  for (int r = 0; r < 4; ++r) { mA[r] = mB[r] = -1e30f; lA[r] = lB[r] = 0.f; }

  const int r0 = t >> 3;
  const int c0 = (t & 7) << 3;
  short8 kr0, kr1, vr0, vr1;

  auto LOADT = [&](int kt) {
    const int kv0 = kt << 6;
    kr0 = *(const short8*)&Kb[(size_t)(kv0 + r0) * DKH + c0];
    kr1 = *(const short8*)&Kb[(size_t)(kv0 + r0 + 32) * DKH + c0];
    vr0 = *(const short8*)&Vb[(size_t)r0 * S_LEN + kv0 + c0];
    vr1 = *(const short8*)&Vb[(size_t)(r0 + 32) * S_LEN + kv0 + c0];
  };
  auto WRITET = [&](int b) {
    *(short8*)&Ks[b][r0 * LDT + c0] = kr0;
    *(short8*)&Ks[b][(r0 + 32) * LDT + c0] = kr1;
    *(short8*)&Vs[b][r0 * LDT + c0] = vr0;
    *(short8*)&Vs[b][(r0 + 32) * LDT + c0] = vr1;
  };

  auto COMPUTE = [&](int buf, const bf16x8* qf, f32x4* o, float* m, float* l,
                     int pslot, bool diag) {
    f32x4 sf[4];
#pragma unroll
    for (int fk = 0; fk < 4; ++fk) {
      f32x4 a = {};
#pragma unroll
      for (int kc = 0; kc < 2; ++kc) {
        bf16x8 kf = *(const bf16x8*)&Ks[buf][(fk * 16 + lr) * LDT + kc * 32 + g * 8];
        a = mfma16x16(qf[kc], kf, a);
      }
      sf[fk] = a;
    }
#pragma unroll
    for (int fk = 0; fk < 4; ++fk)
#pragma unroll
      for (int r = 0; r < 4; ++r)
        sf[fk][r] *= 0.125f;
    if (diag) {
#pragma unroll
      for (int fk = 0; fk < 4; ++fk) {
        const int kvl = fk * 16 + lr;
#pragma unroll
        for (int r = 0; r < 4; ++r)
          if (kvl > w * 16 + g * 4 + r) sf[fk][r] = -1e30f;
      }
    }
    float p[4][4];
#pragma unroll
    for (int r = 0; r < 4; ++r) {
      float x = fmaxf(fmaxf(sf[0][r], sf[1][r]), fmaxf(sf[2][r], sf[3][r]));
#pragma unroll
      for (int off = 1; off < 16; off <<= 1)
        x = fmaxf(x, __shfl_xor(x, off));
      const float mn = fmaxf(m[r], x);
      const float alpha = __expf(m[r] - mn);
      m[r] = mn;
      float rs = 0.f;
#pragma unroll
      for (int fk = 0; fk < 4; ++fk) {
        float pv = __expf(sf[fk][r] - mn);
        p[fk][r] = pv;
        rs += pv;
      }
#pragma unroll
      for (int off = 1; off < 16; off <<= 1)
        rs += __shfl_xor(rs, off);
      l[r] = l[r] * alpha + rs;
#pragma unroll
      for (int d = 0; d < 4; ++d) o[d][r] *= alpha;
    }
#pragma unroll
    for (int fk = 0; fk < 4; ++fk)
#pragma unroll
      for (int r = 0; r < 4; ++r)
        Ps[pslot][(g * 4 + r) * LDT + fk * 16 + lr] = f2bf(p[fk][r]);
#pragma unroll
    for (int kc = 0; kc < 2; ++kc) {
      bf16x8 pf = *(const bf16x8*)&Ps[pslot][lr * LDT + kc * 32 + g * 8];
#pragma unroll
      for (int df = 0; df < 4; ++df) {
        bf16x8 vf = *(const bf16x8*)&Vs[buf][(df * 16 + lr) * LDT + kc * 32 + g * 8];
        o[df] = mfma16x16(pf, vf, o[df]);
      }
    }
  };

  const int nt = tB + 1;
  LOADT(0);
  WRITET(0);
  for (int kt = 0; kt < nt; ++kt) {
    const int cur = kt & 1;
    const bool more = (kt + 1 < nt);
    if (more) LOADT(kt + 1);
    __syncthreads();
    if (kt <= tA) COMPUTE(cur, qfA, oA, mA, lA, w, kt == tA);
    COMPUTE(cur, qfB, oB, mB, lB, 4 + w, kt == tB);
    if (more) WRITET(cur ^ 1);
  }

  const int b = bh >> 4, h = bh & (NHEAD - 1);
#pragma unroll
  for (int df = 0; df < 4; ++df)
#pragma unroll
    for (int r = 0; r < 4; ++r) {
      const int d = df * 16 + lr;
      const int qa = tA * 64 + w * 16 + g * 4 + r;
      const int qb2 = tB * 64 + w * 16 + g * 4 + r;
      if (HS) {
        Ao[((size_t)bh * S_LEN + qa) * DKH + d] = f2bf(oA[df][r] / lA[r]);
        Ao[((size_t)bh * S_LEN + qb2) * DKH + d] = f2bf(oB[df][r] / lB[r]);
      } else {
        Ao[((size_t)(b * S_LEN + qa)) * DMODEL + h * DKH + d] = f2bf(oA[df][r] / lA[r]);
        Ao[((size_t)(b * S_LEN + qb2)) * DMODEL + h * DKH + d] = f2bf(oB[df][r] / lB[r]);
      }
    }
}

extern "C" void kernel_launch(void* const* d_in, const int* in_sizes, int n_in,
                              void* d_out, int out_size, void* d_ws, size_t ws_size,
                              hipStream_t stream)
{
  (void)in_sizes; (void)n_in; (void)out_size;
  const float* q  = (const float*)d_in[0];
  const float* k  = (const float*)d_in[1];
  const float* v  = (const float*)d_in[2];
  const float* Wq = (const float*)d_in[4];
  const float* bq = (const float*)d_in[5];
  const float* Wk = (const float*)d_in[6];
  const float* bk = (const float*)d_in[7];
  const float* Wv = (const float*)d_in[8];
  const float* bv = (const float*)d_in[9];
  const float* Wo = (const float*)d_in[10];
  const float* bo = (const float*)d_in[11];

  char* ws = (char*)d_ws;
  const size_t MB = 1024 * 1024;

  if (ws_size >= 40 * MB) {
    u16* Wqb = (u16*)(ws);                // 2 MB each
    u16* Wkb = (u16*)(ws + 2 * MB);
    u16* Wvb = (u16*)(ws + 4 * MB);
    u16* Wob = (u16*)(ws + 6 * MB);
    u16* Qh  = (u16*)(ws + 8 * MB);       // 8 MB each
    u16* Kh  = (u16*)(ws + 16 * MB);
    u16* Vt  = (u16*)(ws + 24 * MB);
    u16* Ao  = (u16*)(ws + 32 * MB);

    conv_w<<<dim3(512, 4), 256, 0, stream>>>(Wq, Wk, Wv, Wo, Wqb, Wkb, Wvb, Wob);
    proj_gemm<<<dim3(8, 32, 3), 256, 0, stream>>>(q, k, v, Wqb, Wkb, Wvb,
                                                  bq, bk, bv, Qh, Kh, Vt);
    attn_fwd<true><<<dim3(16, 2 * NHEAD), 256, 0, stream>>>(Qh, Kh, Vt, Ao);
    out_gemm<<<dim3(8, 32), 256, 0, stream>>>(Ao, Wob, bo, (float*)d_out);
  } else {
    // R4 fallback (32 MB scratch)
    u16* Qh = (u16*)(ws);
    u16* Kh = (u16*)(ws + 8 * MB);
    u16* Vt = (u16*)(ws + 16 * MB);
    u16* Ao = (u16*)(ws + 24 * MB);
    const int M = 2 * S_LEN, N = DMODEL, K = DMODEL;
    dim3 gg(N / 64, M / 64), bb(256);
    gemm64<true, 1><<<gg, bb, 0, stream>>>(q, Wq, bq, Qh, M, N, K);
    gemm64<true, 1><<<gg, bb, 0, stream>>>(k, Wk, bk, Kh, M, N, K);
    gemm64<true, 2><<<gg, bb, 0, stream>>>(v, Wv, bv, Vt, M, N, K);
    attn_fwd<false><<<dim3(16, 2 * NHEAD), bb, 0, stream>>>(Qh, Kh, Vt, Ao);
    gemm64<false, 0><<<gg, bb, 0, stream>>>(Ao, Wo, bo, d_out, M, N, K);
  }
}

// Round 6
// 161.085 us; speedup vs baseline: 1.9874x; 1.1261x over previous
//
#include <hip/hip_runtime.h>

// MHA forward: B=2, S=2048, D=1024, H=16, DK=64. fp32 in/out, bf16 MFMA compute.
// R6: GEMM fixes over R5 (attention unchanged).
//  - T2 XOR swizzle (both-sides): gl_lds keeps LDS linear, global source col8
//    pre-XOR'd with row&7; reg-staged A swizzles the LDS write address;
//    fragment reads apply the same XOR.  (R5: 9.4M bank conflicts, 16-way)
//  - bijective XCD relabel: co-locate a row-panel's 8 col-blocks on one XCD
//    (R5 fetched 200 MB vs 54 ideal: every XCD streamed all of A).

#define S_LEN 2048
#define NHEAD 16
#define DMODEL 1024
#define DKH 64
#define LDT 88   // padded LDS row stride for 64-wide tiles (attn + fallback)

typedef unsigned short u16;
typedef __attribute__((ext_vector_type(8))) short short8;
typedef __attribute__((ext_vector_type(8))) __bf16 bf16x8;
typedef __attribute__((ext_vector_type(4))) float f32x4;

__device__ inline u16 f2bf(float f) {
  return __builtin_bit_cast(u16, (__bf16)f);   // v_cvt RNE
}

__device__ inline f32x4 mfma16x16(bf16x8 a, bf16x8 b, f32x4 c) {
  return __builtin_amdgcn_mfma_f32_16x16x32_bf16(a, b, c, 0, 0, 0);
}

__device__ inline short8 pack8(float4 a, float4 b) {
  short8 r;
  r[0] = (short)f2bf(a.x); r[1] = (short)f2bf(a.y);
  r[2] = (short)f2bf(a.z); r[3] = (short)f2bf(a.w);
  r[4] = (short)f2bf(b.x); r[5] = (short)f2bf(b.y);
  r[6] = (short)f2bf(b.z); r[7] = (short)f2bf(b.w);
  return r;
}

typedef const __attribute__((address_space(1))) unsigned GU32;
typedef __attribute__((address_space(3))) unsigned LU32;
__device__ inline void gl2lds16(const void* g, void* l) {
  __builtin_amdgcn_global_load_lds((GU32*)g, (LU32*)l, 16, 0, 0);
}

// swizzled elem-offset into a [rows][64] bf16 tile; col8 = 16B-slot index 0..7
#define SWZ(row, col8) (((row) * 8 + ((col8) ^ ((row) & 7))) * 8)

// ---------- weight conversion: 4x [1024x1024] f32 -> bf16 ----------
__global__ __launch_bounds__(256)
void conv_w(const float* __restrict__ w0, const float* __restrict__ w1,
            const float* __restrict__ w2, const float* __restrict__ w3,
            u16* __restrict__ o0, u16* __restrict__ o1,
            u16* __restrict__ o2, u16* __restrict__ o3)
{
  const int z = blockIdx.y;
  const float* s = z == 0 ? w0 : z == 1 ? w1 : z == 2 ? w2 : w3;
  u16* d = z == 0 ? o0 : z == 1 ? o1 : z == 2 ? o2 : o3;
  const int i = (blockIdx.x * 256 + threadIdx.x) * 8;
  float4 a = *(const float4*)&s[i];
  float4 b = *(const float4*)&s[i + 4];
  *(short8*)&d[i] = pack8(a, b);
}

// ---------- batched projection GEMMs (q,k,v) x (Wq,Wk,Wv), 128x128, BK=64 ----
// z=0,1 -> bf16 head-split [bh][s][dk]; z=2 -> bf16 transposed [bh][dk][s]
__global__ __launch_bounds__(256)
void proj_gemm(const float* __restrict__ Aq, const float* __restrict__ Akk,
               const float* __restrict__ Av,
               const u16* __restrict__ Bq, const u16* __restrict__ Bk,
               const u16* __restrict__ Bv,
               const float* __restrict__ cq, const float* __restrict__ ck,
               const float* __restrict__ cv,
               u16* __restrict__ Oq, u16* __restrict__ Ok, u16* __restrict__ Ov)
{
  __shared__ u16 SM[2 * 128 * 64];
  u16* As = SM;
  u16* Bs = SM + 128 * 64;

  // bijective XCD relabel: hw%8 = XCD (round-robin). Give each row-panel
  // (zz,py) to exactly one XCD; its 8 col-blocks share the A-panel in L2.
  const int hw = blockIdx.x + (blockIdx.y << 3) + (blockIdx.z << 8);  // 0..767
  const int xcd = hw & 7, sq = hw >> 3;          // sq 0..95
  const int pan = sq % 12, xb = sq / 12;         // 12 panels/XCD, 8 col-blocks
  const int p = pan * 8 + xcd;                   // 0..95 global panel
  const int zz = p >> 5, py = p & 31;

  const float* Af = zz == 0 ? Aq : zz == 1 ? Akk : Av;
  const u16* Wb = zz == 0 ? Bq : zz == 1 ? Bk : Bv;
  const float* bias = zz == 0 ? cq : zz == 1 ? ck : cv;

  const int t = threadIdx.x;
  const int lane = t & 63;
  const int wv = t >> 6;
  const int wm = wv >> 1, wn = wv & 1;        // 2x2 waves, each 64x64
  const int g = lane >> 4, lr = lane & 15;
  const int bm = py << 7, bn = xb << 7;
  const int K = DMODEL;

  f32x4 acc[4][4] = {};
  for (int kt = 0; kt < K / 64; ++kt) {
    const int k0 = kt << 6;
    __syncthreads();
#pragma unroll
    for (int i = 0; i < 4; ++i) {
      int c = t + (i << 8);
      int row = c >> 3, col8 = c & 7;
      // B: gl_lds, LDS linear dest, SOURCE pre-swizzled (rule #21)
      int c8s = col8 ^ (row & 7);
      gl2lds16(&Wb[(size_t)(bn + row) * K + k0 + c8s * 8], &Bs[c * 8]);
      // A: fp32 -> bf16 reg-staged, LDS WRITE swizzled, source linear
      const float* src = &Af[(size_t)(bm + row) * K + k0 + col8 * 8];
      float4 x = *(const float4*)src;
      float4 y = *(const float4*)(src + 4);
      *(short8*)&As[SWZ(row, col8)] = pack8(x, y);
    }
    __syncthreads();
    bf16x8 af[2][4], bf[2][4];
#pragma unroll
    for (int kc = 0; kc < 2; ++kc)
#pragma unroll
      for (int f = 0; f < 4; ++f) {
        af[kc][f] = *(const bf16x8*)&As[SWZ(wm * 64 + f * 16 + lr, kc * 4 + g)];
        bf[kc][f] = *(const bf16x8*)&Bs[SWZ(wn * 64 + f * 16 + lr, kc * 4 + g)];
      }
#pragma unroll
    for (int kc = 0; kc < 2; ++kc)
#pragma unroll
      for (int fm = 0; fm < 4; ++fm)
#pragma unroll
        for (int fn = 0; fn < 4; ++fn)
          acc[fm][fn] = mfma16x16(af[kc][fm], bf[kc][fn], acc[fm][fn]);
  }

  if (zz == 2) {
    // V: write transposed [bh][dk][s] via two-pass LDS transpose (tile spans 2 heads)
    u16* TL = SM;                              // 64 x 132 bf16
    const int b = bm >> 11, s0 = bm & (S_LEN - 1), h0 = bn >> 6;
#pragma unroll
    for (int hh = 0; hh < 2; ++hh) {
      __syncthreads();
      if (wn == hh) {
#pragma unroll
        for (int fm = 0; fm < 4; ++fm)
#pragma unroll
          for (int fn = 0; fn < 4; ++fn) {
            const int lch = fn * 16 + lr;      // dk within head
            const float bb = bias[bn + hh * 64 + lch];
#pragma unroll
            for (int r = 0; r < 4; ++r)
              TL[lch * 132 + wm * 64 + fm * 16 + g * 4 + r] = f2bf(acc[fm][fn][r] + bb);
          }
      }
      __syncthreads();
#pragma unroll
      for (int i = 0; i < 4; ++i) {
        int c = t + (i << 8);
        int dk = c >> 4, sc = (c & 15) << 3;
        short8 vv = *(const short8*)&TL[dk * 132 + sc];
        *(short8*)&Ov[(((size_t)(b * NHEAD + h0 + hh)) * DKH + dk) * S_LEN + s0 + sc] = vv;
      }
    }
  } else {
    u16* Out = zz == 0 ? Oq : Ok;
#pragma unroll
    for (int fm = 0; fm < 4; ++fm)
#pragma unroll
      for (int fn = 0; fn < 4; ++fn) {
        const int col = bn + wn * 64 + fn * 16 + lr;
        const int h = col >> 6, dk = col & (DKH - 1);
        const float bb = bias[col];
#pragma unroll
        for (int r = 0; r < 4; ++r) {
          const int row = bm + wm * 64 + fm * 16 + g * 4 + r;
          const int b = row >> 11, s = row & (S_LEN - 1);
          Out[(((size_t)(b * NHEAD + h)) * S_LEN + s) * DKH + dk] = f2bf(acc[fm][fn][r] + bb);
        }
      }
  }
}

// ---------- O-projection: Ao(head-split bf16) @ Wo^T + bo -> f32 out ----------
__global__ __launch_bounds__(256)
void out_gemm(const u16* __restrict__ Ao, const u16* __restrict__ Wb,
              const float* __restrict__ bias, float* __restrict__ Out)
{
  __shared__ u16 SM[2 * 128 * 64];
  u16* As = SM;
  u16* Bs = SM + 128 * 64;

  const int hw = blockIdx.x + (blockIdx.y << 3);   // 0..255
  const int xcd = hw & 7, sq = hw >> 3;            // sq 0..31
  const int pan = sq & 3, xb = sq >> 2;            // 4 panels/XCD, 8 col-blocks
  const int prow = pan * 8 + xcd;                  // 0..31

  const int t = threadIdx.x;
  const int lane = t & 63;
  const int wv = t >> 6;
  const int wm = wv >> 1, wn = wv & 1;
  const int g = lane >> 4, lr = lane & 15;
  const int bm = prow << 7, bn = xb << 7;
  const int K = DMODEL;

  f32x4 acc[4][4] = {};
  for (int kt = 0; kt < K / 64; ++kt) {
    const int k0 = kt << 6;
    __syncthreads();
#pragma unroll
    for (int i = 0; i < 4; ++i) {
      int c = t + (i << 8);
      int row = c >> 3, col8 = c & 7;
      int c8s = col8 ^ (row & 7);
      // A logical (row=b*2048+s, k=h*64+dk) from head-split Ao, source-swizzled
      int grow = bm + row;
      int b = grow >> 11, s = grow & (S_LEN - 1);
      int k = k0 + c8s * 8;
      int h = k >> 6, dk = k & (DKH - 1);
      gl2lds16(&Ao[(((size_t)(b * NHEAD + h)) * S_LEN + s) * DKH + dk], &As[c * 8]);
      gl2lds16(&Wb[(size_t)(bn + row) * K + k0 + c8s * 8], &Bs[c * 8]);
    }
    __syncthreads();
    bf16x8 af[2][4], bf[2][4];
#pragma unroll
    for (int kc = 0; kc < 2; ++kc)
#pragma unroll
      for (int f = 0; f < 4; ++f) {
        af[kc][f] = *(const bf16x8*)&As[SWZ(wm * 64 + f * 16 + lr, kc * 4 + g)];
        bf[kc][f] = *(const bf16x8*)&Bs[SWZ(wn * 64 + f * 16 + lr, kc * 4 + g)];
      }
#pragma unroll
    for (int kc = 0; kc < 2; ++kc)
#pragma unroll
      for (int fm = 0; fm < 4; ++fm)
#pragma unroll
        for (int fn = 0; fn < 4; ++fn)
          acc[fm][fn] = mfma16x16(af[kc][fm], bf[kc][fn], acc[fm][fn]);
  }
#pragma unroll
  for (int fm = 0; fm < 4; ++fm)
#pragma unroll
    for (int fn = 0; fn < 4; ++fn) {
      const int col = bn + wn * 64 + fn * 16 + lr;
      const float bb = bias[col];
#pragma unroll
      for (int r = 0; r < 4; ++r) {
        const int row = bm + wm * 64 + fm * 16 + g * 4 + r;
        Out[(size_t)row * DMODEL + col] = acc[fm][fn][r] + bb;
      }
    }
}

// ================= old R4 path (fallback if ws_size < 40 MB) =================
template<bool AF32, int OMODE>
__global__ __launch_bounds__(256)
void gemm64(const void* __restrict__ Ap, const float* __restrict__ Bt,
            const float* __restrict__ bias, void* __restrict__ outp,
            int M, int N, int K)
{
  __shared__ u16 As[64 * LDT];
  __shared__ u16 Bs[64 * LDT];
  const int t = threadIdx.x;
  const int lane = t & 63;
  const int wv = t >> 6;
  const int wm = wv >> 1, wn = wv & 1;
  const int g = lane >> 4, lr = lane & 15;
  const int bm = blockIdx.y << 6, bn = blockIdx.x << 6;

  f32x4 acc[2][2] = {};
  const int nk = K >> 6;
  for (int kt = 0; kt < nk; ++kt) {
    const int k0 = kt << 6;
    __syncthreads();
#pragma unroll
    for (int i = 0; i < 2; ++i) {
      int c = t + (i << 8);
      int row = c >> 3, col = (c & 7) << 3;
      short8 av;
      if (AF32) {
        const float* Af = (const float*)Ap;
        const float4* pa = (const float4*)&Af[(size_t)(bm + row) * K + k0 + col];
        av = pack8(pa[0], pa[1]);
      } else {
        av = *(const short8*)&((const u16*)Ap)[(size_t)(bm + row) * K + k0 + col];
      }
      *(short8*)&As[row * LDT + col] = av;
      const float4* pb = (const float4*)&Bt[(size_t)(bn + row) * K + k0 + col];
      *(short8*)&Bs[row * LDT + col] = pack8(pb[0], pb[1]);
    }
    __syncthreads();
    bf16x8 af[2][2], bfr[2][2];
#pragma unroll
    for (int kc = 0; kc < 2; ++kc) {
#pragma unroll
      for (int fm = 0; fm < 2; ++fm)
        af[kc][fm] = *(const bf16x8*)&As[(wm * 32 + fm * 16 + lr) * LDT + kc * 32 + g * 8];
#pragma unroll
      for (int fn = 0; fn < 2; ++fn)
        bfr[kc][fn] = *(const bf16x8*)&Bs[(wn * 32 + fn * 16 + lr) * LDT + kc * 32 + g * 8];
    }
#pragma unroll
    for (int kc = 0; kc < 2; ++kc)
#pragma unroll
      for (int fm = 0; fm < 2; ++fm)
#pragma unroll
        for (int fn = 0; fn < 2; ++fn)
          acc[fm][fn] = mfma16x16(af[kc][fm], bfr[kc][fn], acc[fm][fn]);
  }
  if (OMODE == 2) {
    u16* TL = As;
    __syncthreads();
#pragma unroll
    for (int fm = 0; fm < 2; ++fm)
#pragma unroll
      for (int fn = 0; fn < 2; ++fn) {
        const int lc = wn * 32 + fn * 16 + lr;
        const float bb = bias[bn + lc];
#pragma unroll
        for (int r = 0; r < 4; ++r) {
          const int lrow = wm * 32 + fm * 16 + g * 4 + r;
          TL[lc * LDT + lrow] = f2bf(acc[fm][fn][r] + bb);
        }
      }
    __syncthreads();
    const int bh = (bm >> 11) * NHEAD + (bn >> 6);
    const int s0 = bm & (S_LEN - 1);
#pragma unroll
    for (int i = 0; i < 2; ++i) {
      int c = t + (i << 8);
      int dr = c >> 3, sc = (c & 7) << 3;
      short8 vv = *(const short8*)&TL[dr * LDT + sc];
      *(short8*)&((u16*)outp)[((size_t)bh * DKH + dr) * S_LEN + s0 + sc] = vv;
    }
  } else {
#pragma unroll
    for (int fm = 0; fm < 2; ++fm)
#pragma unroll
      for (int fn = 0; fn < 2; ++fn) {
        const int col = bn + wn * 32 + fn * 16 + lr;
        const float bb = bias[col];
#pragma unroll
        for (int r = 0; r < 4; ++r) {
          const int row = bm + wm * 32 + fm * 16 + g * 4 + r;
          float vv = acc[fm][fn][r] + bb;
          if (OMODE == 1) {
            int b = row >> 11, s = row & (S_LEN - 1);
            int h = col >> 6, dk = col & (DKH - 1);
            ((u16*)outp)[(((size_t)(b * NHEAD + h)) * S_LEN + s) * DKH + dk] = f2bf(vv);
          } else {
            ((float*)outp)[(size_t)row * N + col] = vv;
          }
        }
      }
  }
}

// Flash attention, causal, paired q-tiles {p, 31-p}. HS: Ao head-split layout.
template<bool HS>
__global__ __launch_bounds__(256)
void attn_fwd(const u16* __restrict__ Qh, const u16* __restrict__ Kh,
              const u16* __restrict__ Vtg, u16* __restrict__ Ao)
{
  __shared__ u16 Ks[2][64 * LDT];
  __shared__ u16 Vs[2][64 * LDT];
  __shared__ u16 Ps[8][16 * LDT];
  const int t = threadIdx.x, lane = t & 63, w = t >> 6;
  const int g = lane >> 4, lr = lane & 15;
  const int bh = blockIdx.y;
  const int pA = blockIdx.x;
  const int tA = pA, tB = 31 - pA;
  const u16* Qb = Qh + (size_t)bh * S_LEN * DKH;
  const u16* Kb = Kh + (size_t)bh * S_LEN * DKH;
  const u16* Vb = Vtg + (size_t)bh * DKH * S_LEN;

  bf16x8 qfA[2], qfB[2];
#pragma unroll
  for (int kc = 0; kc < 2; ++kc) {
    qfA[kc] = *(const bf16x8*)&Qb[(size_t)(tA * 64 + w * 16 + lr) * DKH + kc * 32 + g * 8];
    qfB[kc] = *(const bf16x8*)&Qb[(size_t)(tB * 64 + w * 16 + lr) * DKH + kc * 32 + g * 8];
  }

  f32x4 oA[4] = {}, oB[4] = {};
  float mA[4], lA[4], mB[4], lB[4];
#pragma unroll
  for (int r = 0; r < 4; ++r) { mA[r] = mB[r] = -1e30f; lA[r] = lB[r] = 0.f; }

  const int r0 = t >> 3;
  const int c0 = (t & 7) << 3;
  short8 kr0, kr1, vr0, vr1;

  auto LOADT = [&](int kt) {
    const int kv0 = kt << 6;
    kr0 = *(const short8*)&Kb[(size_t)(kv0 + r0) * DKH + c0];
    kr1 = *(const short8*)&Kb[(size_t)(kv0 + r0 + 32) * DKH + c0];
    vr0 = *(const short8*)&Vb[(size_t)r0 * S_LEN + kv0 + c0];
    vr1 = *(const short8*)&Vb[(size_t)(r0 + 32) * S_LEN + kv0 + c0];
  };
  auto WRITET = [&](int b) {
    *(short8*)&Ks[b][r0 * LDT + c0] = kr0;
    *(short8*)&Ks[b][(r0 + 32) * LDT + c0] = kr1;
    *(short8*)&Vs[b][r0 * LDT + c0] = vr0;
    *(short8*)&Vs[b][(r0 + 32) * LDT + c0] = vr1;
  };

  auto COMPUTE = [&](int buf, const bf16x8* qf, f32x4* o, float* m, float* l,
                     int pslot, bool diag) {
    f32x4 sf[4];
#pragma unroll
    for (int fk = 0; fk < 4; ++fk) {
      f32x4 a = {};
#pragma unroll
      for (int kc = 0; kc < 2; ++kc) {
        bf16x8 kf = *(const bf16x8*)&Ks[buf][(fk * 16 + lr) * LDT + kc * 32 + g * 8];
        a = mfma16x16(qf[kc], kf, a);
      }
      sf[fk] = a;
    }
#pragma unroll
    for (int fk = 0; fk < 4; ++fk)
#pragma unroll
      for (int r = 0; r < 4; ++r)
        sf[fk][r] *= 0.125f;
    if (diag) {
#pragma unroll
      for (int fk = 0; fk < 4; ++fk) {
        const int kvl = fk * 16 + lr;
#pragma unroll
        for (int r = 0; r < 4; ++r)
          if (kvl > w * 16 + g * 4 + r) sf[fk][r] = -1e30f;
      }
    }
    float p[4][4];
#pragma unroll
    for (int r = 0; r < 4; ++r) {
      float x = fmaxf(fmaxf(sf[0][r], sf[1][r]), fmaxf(sf[2][r], sf[3][r]));
#pragma unroll
      for (int off = 1; off < 16; off <<= 1)
        x = fmaxf(x, __shfl_xor(x, off));
      const float mn = fmaxf(m[r], x);
      const float alpha = __expf(m[r] - mn);
      m[r] = mn;
      float rs = 0.f;
#pragma unroll
      for (int fk = 0; fk < 4; ++fk) {
        float pv = __expf(sf[fk][r] - mn);
        p[fk][r] = pv;
        rs += pv;
      }
#pragma unroll
      for (int off = 1; off < 16; off <<= 1)
        rs += __shfl_xor(rs, off);
      l[r] = l[r] * alpha + rs;
#pragma unroll
      for (int d = 0; d < 4; ++d) o[d][r] *= alpha;
    }
#pragma unroll
    for (int fk = 0; fk < 4; ++fk)
#pragma unroll
      for (int r = 0; r < 4; ++r)
        Ps[pslot][(g * 4 + r) * LDT + fk * 16 + lr] = f2bf(p[fk][r]);
#pragma unroll
    for (int kc = 0; kc < 2; ++kc) {
      bf16x8 pf = *(const bf16x8*)&Ps[pslot][lr * LDT + kc * 32 + g * 8];
#pragma unroll
      for (int df = 0; df < 4; ++df) {
        bf16x8 vf = *(const bf16x8*)&Vs[buf][(df * 16 + lr) * LDT + kc * 32 + g * 8];
        o[df] = mfma16x16(pf, vf, o[df]);
      }
    }
  };

  const int nt = tB + 1;
  LOADT(0);
  WRITET(0);
  for (int kt = 0; kt < nt; ++kt) {
    const int cur = kt & 1;
    const bool more = (kt + 1 < nt);
    if (more) LOADT(kt + 1);
    __syncthreads();
    if (kt <= tA) COMPUTE(cur, qfA, oA, mA, lA, w, kt == tA);
    COMPUTE(cur, qfB, oB, mB, lB, 4 + w, kt == tB);
    if (more) WRITET(cur ^ 1);
  }

  const int b = bh >> 4, h = bh & (NHEAD - 1);
#pragma unroll
  for (int df = 0; df < 4; ++df)
#pragma unroll
    for (int r = 0; r < 4; ++r) {
      const int d = df * 16 + lr;
      const int qa = tA * 64 + w * 16 + g * 4 + r;
      const int qb2 = tB * 64 + w * 16 + g * 4 + r;
      if (HS) {
        Ao[((size_t)bh * S_LEN + qa) * DKH + d] = f2bf(oA[df][r] / lA[r]);
        Ao[((size_t)bh * S_LEN + qb2) * DKH + d] = f2bf(oB[df][r] / lB[r]);
      } else {
        Ao[((size_t)(b * S_LEN + qa)) * DMODEL + h * DKH + d] = f2bf(oA[df][r] / lA[r]);
        Ao[((size_t)(b * S_LEN + qb2)) * DMODEL + h * DKH + d] = f2bf(oB[df][r] / lB[r]);
      }
    }
}

extern "C" void kernel_launch(void* const* d_in, const int* in_sizes, int n_in,
                              void* d_out, int out_size, void* d_ws, size_t ws_size,
                              hipStream_t stream)
{
  (void)in_sizes; (void)n_in; (void)out_size;
  const float* q  = (const float*)d_in[0];
  const float* k  = (const float*)d_in[1];
  const float* v  = (const float*)d_in[2];
  const float* Wq = (const float*)d_in[4];
  const float* bq = (const float*)d_in[5];
  const float* Wk = (const float*)d_in[6];
  const float* bk = (const float*)d_in[7];
  const float* Wv = (const float*)d_in[8];
  const float* bv = (const float*)d_in[9];
  const float* Wo = (const float*)d_in[10];
  const float* bo = (const float*)d_in[11];

  char* ws = (char*)d_ws;
  const size_t MB = 1024 * 1024;

  if (ws_size >= 40 * MB) {
    u16* Wqb = (u16*)(ws);                // 2 MB each
    u16* Wkb = (u16*)(ws + 2 * MB);
    u16* Wvb = (u16*)(ws + 4 * MB);
    u16* Wob = (u16*)(ws + 6 * MB);
    u16* Qh  = (u16*)(ws + 8 * MB);       // 8 MB each
    u16* Kh  = (u16*)(ws + 16 * MB);
    u16* Vt  = (u16*)(ws + 24 * MB);
    u16* Ao  = (u16*)(ws + 32 * MB);

    conv_w<<<dim3(512, 4), 256, 0, stream>>>(Wq, Wk, Wv, Wo, Wqb, Wkb, Wvb, Wob);
    proj_gemm<<<dim3(8, 32, 3), 256, 0, stream>>>(q, k, v, Wqb, Wkb, Wvb,
                                                  bq, bk, bv, Qh, Kh, Vt);
    attn_fwd<true><<<dim3(16, 2 * NHEAD), 256, 0, stream>>>(Qh, Kh, Vt, Ao);
    out_gemm<<<dim3(8, 32), 256, 0, stream>>>(Ao, Wob, bo, (float*)d_out);
  } else {
    // R4 fallback (32 MB scratch)
    u16* Qh = (u16*)(ws);
    u16* Kh = (u16*)(ws + 8 * MB);
    u16* Vt = (u16*)(ws + 16 * MB);
    u16* Ao = (u16*)(ws + 24 * MB);
    const int M = 2 * S_LEN, N = DMODEL, K = DMODEL;
    dim3 gg(N / 64, M / 64), bb(256);
    gemm64<true, 1><<<gg, bb, 0, stream>>>(q, Wq, bq, Qh, M, N, K);
    gemm64<true, 1><<<gg, bb, 0, stream>>>(k, Wk, bk, Kh, M, N, K);
    gemm64<true, 2><<<gg, bb, 0, stream>>>(v, Wv, bv, Vt, M, N, K);
    attn_fwd<false><<<dim3(16, 2 * NHEAD), bb, 0, stream>>>(Qh, Kh, Vt, Ao);
    gemm64<false, 0><<<gg, bb, 0, stream>>>(Ao, Wo, bo, d_out, M, N, K);
  }
}

// Round 7
// 139.909 us; speedup vs baseline: 2.2881x; 1.1514x over previous
//
#include <hip/hip_runtime.h>

// MHA forward: B=2, S=2048, D=1024, H=16, DK=64. fp32 in/out, bf16 MFMA compute.
// R7: attention softmax restructure (GEMMs unchanged from R6).
//  - swapped QK^T: mfma(K,Q) -> S[kv][q], q-row lives in-lane (q=lane&15,
//    kv=fk*16+4g+r). Row reduce = 15 in-reg fmax + 2 shfl (was 4x 4-step
//    butterflies x2 = 32 shfl/COMPUTE). m,l become scalars.
//  - T13 defer-rescale (THR=8 scaled = 64 raw): skip O-rescale when max growth small
//  - P-store: 4x ds_write_b64 (r contiguous) instead of 16 scalar stores

#define S_LEN 2048
#define NHEAD 16
#define DMODEL 1024
#define DKH 64
#define LDT 88   // padded LDS row stride for 64-wide tiles (attn + fallback)

typedef unsigned short u16;
typedef __attribute__((ext_vector_type(4))) short short4v;
typedef __attribute__((ext_vector_type(8))) short short8;
typedef __attribute__((ext_vector_type(8))) __bf16 bf16x8;
typedef __attribute__((ext_vector_type(4))) float f32x4;

__device__ inline u16 f2bf(float f) {
  return __builtin_bit_cast(u16, (__bf16)f);   // v_cvt RNE
}

__device__ inline f32x4 mfma16x16(bf16x8 a, bf16x8 b, f32x4 c) {
  return __builtin_amdgcn_mfma_f32_16x16x32_bf16(a, b, c, 0, 0, 0);
}

__device__ inline short8 pack8(float4 a, float4 b) {
  short8 r;
  r[0] = (short)f2bf(a.x); r[1] = (short)f2bf(a.y);
  r[2] = (short)f2bf(a.z); r[3] = (short)f2bf(a.w);
  r[4] = (short)f2bf(b.x); r[5] = (short)f2bf(b.y);
  r[6] = (short)f2bf(b.z); r[7] = (short)f2bf(b.w);
  return r;
}

typedef const __attribute__((address_space(1))) unsigned GU32;
typedef __attribute__((address_space(3))) unsigned LU32;
__device__ inline void gl2lds16(const void* g, void* l) {
  __builtin_amdgcn_global_load_lds((GU32*)g, (LU32*)l, 16, 0, 0);
}

// swizzled elem-offset into a [rows][64] bf16 tile; col8 = 16B-slot index 0..7
#define SWZ(row, col8) (((row) * 8 + ((col8) ^ ((row) & 7))) * 8)

// ---------- weight conversion: 4x [1024x1024] f32 -> bf16 ----------
__global__ __launch_bounds__(256)
void conv_w(const float* __restrict__ w0, const float* __restrict__ w1,
            const float* __restrict__ w2, const float* __restrict__ w3,
            u16* __restrict__ o0, u16* __restrict__ o1,
            u16* __restrict__ o2, u16* __restrict__ o3)
{
  const int z = blockIdx.y;
  const float* s = z == 0 ? w0 : z == 1 ? w1 : z == 2 ? w2 : w3;
  u16* d = z == 0 ? o0 : z == 1 ? o1 : z == 2 ? o2 : o3;
  const int i = (blockIdx.x * 256 + threadIdx.x) * 8;
  float4 a = *(const float4*)&s[i];
  float4 b = *(const float4*)&s[i + 4];
  *(short8*)&d[i] = pack8(a, b);
}

// ---------- batched projection GEMMs (q,k,v) x (Wq,Wk,Wv), 128x128, BK=64 ----
__global__ __launch_bounds__(256)
void proj_gemm(const float* __restrict__ Aq, const float* __restrict__ Akk,
               const float* __restrict__ Av,
               const u16* __restrict__ Bq, const u16* __restrict__ Bk,
               const u16* __restrict__ Bv,
               const float* __restrict__ cq, const float* __restrict__ ck,
               const float* __restrict__ cv,
               u16* __restrict__ Oq, u16* __restrict__ Ok, u16* __restrict__ Ov)
{
  __shared__ u16 SM[2 * 128 * 64];
  u16* As = SM;
  u16* Bs = SM + 128 * 64;

  const int hw = blockIdx.x + (blockIdx.y << 3) + (blockIdx.z << 8);  // 0..767
  const int xcd = hw & 7, sq = hw >> 3;
  const int pan = sq % 12, xb = sq / 12;
  const int p = pan * 8 + xcd;
  const int zz = p >> 5, py = p & 31;

  const float* Af = zz == 0 ? Aq : zz == 1 ? Akk : Av;
  const u16* Wb = zz == 0 ? Bq : zz == 1 ? Bk : Bv;
  const float* bias = zz == 0 ? cq : zz == 1 ? ck : cv;

  const int t = threadIdx.x;
  const int lane = t & 63;
  const int wv = t >> 6;
  const int wm = wv >> 1, wn = wv & 1;
  const int g = lane >> 4, lr = lane & 15;
  const int bm = py << 7, bn = xb << 7;
  const int K = DMODEL;

  f32x4 acc[4][4] = {};
  for (int kt = 0; kt < K / 64; ++kt) {
    const int k0 = kt << 6;
    __syncthreads();
#pragma unroll
    for (int i = 0; i < 4; ++i) {
      int c = t + (i << 8);
      int row = c >> 3, col8 = c & 7;
      int c8s = col8 ^ (row & 7);
      gl2lds16(&Wb[(size_t)(bn + row) * K + k0 + c8s * 8], &Bs[c * 8]);
      const float* src = &Af[(size_t)(bm + row) * K + k0 + col8 * 8];
      float4 x = *(const float4*)src;
      float4 y = *(const float4*)(src + 4);
      *(short8*)&As[SWZ(row, col8)] = pack8(x, y);
    }
    __syncthreads();
    bf16x8 af[2][4], bf[2][4];
#pragma unroll
    for (int kc = 0; kc < 2; ++kc)
#pragma unroll
      for (int f = 0; f < 4; ++f) {
        af[kc][f] = *(const bf16x8*)&As[SWZ(wm * 64 + f * 16 + lr, kc * 4 + g)];
        bf[kc][f] = *(const bf16x8*)&Bs[SWZ(wn * 64 + f * 16 + lr, kc * 4 + g)];
      }
#pragma unroll
    for (int kc = 0; kc < 2; ++kc)
#pragma unroll
      for (int fm = 0; fm < 4; ++fm)
#pragma unroll
        for (int fn = 0; fn < 4; ++fn)
          acc[fm][fn] = mfma16x16(af[kc][fm], bf[kc][fn], acc[fm][fn]);
  }

  if (zz == 2) {
    u16* TL = SM;
    const int b = bm >> 11, s0 = bm & (S_LEN - 1), h0 = bn >> 6;
#pragma unroll
    for (int hh = 0; hh < 2; ++hh) {
      __syncthreads();
      if (wn == hh) {
#pragma unroll
        for (int fm = 0; fm < 4; ++fm)
#pragma unroll
          for (int fn = 0; fn < 4; ++fn) {
            const int lch = fn * 16 + lr;
            const float bb = bias[bn + hh * 64 + lch];
#pragma unroll
            for (int r = 0; r < 4; ++r)
              TL[lch * 132 + wm * 64 + fm * 16 + g * 4 + r] = f2bf(acc[fm][fn][r] + bb);
          }
      }
      __syncthreads();
#pragma unroll
      for (int i = 0; i < 4; ++i) {
        int c = t + (i << 8);
        int dk = c >> 4, sc = (c & 15) << 3;
        short8 vv = *(const short8*)&TL[dk * 132 + sc];
        *(short8*)&Ov[(((size_t)(b * NHEAD + h0 + hh)) * DKH + dk) * S_LEN + s0 + sc] = vv;
      }
    }
  } else {
    u16* Out = zz == 0 ? Oq : Ok;
#pragma unroll
    for (int fm = 0; fm < 4; ++fm)
#pragma unroll
      for (int fn = 0; fn < 4; ++fn) {
        const int col = bn + wn * 64 + fn * 16 + lr;
        const int h = col >> 6, dk = col & (DKH - 1);
        const float bb = bias[col];
#pragma unroll
        for (int r = 0; r < 4; ++r) {
          const int row = bm + wm * 64 + fm * 16 + g * 4 + r;
          const int b = row >> 11, s = row & (S_LEN - 1);
          Out[(((size_t)(b * NHEAD + h)) * S_LEN + s) * DKH + dk] = f2bf(acc[fm][fn][r] + bb);
        }
      }
  }
}

// ---------- O-projection: Ao(head-split bf16) @ Wo^T + bo -> f32 out ----------
__global__ __launch_bounds__(256)
void out_gemm(const u16* __restrict__ Ao, const u16* __restrict__ Wb,
              const float* __restrict__ bias, float* __restrict__ Out)
{
  __shared__ u16 SM[2 * 128 * 64];
  u16* As = SM;
  u16* Bs = SM + 128 * 64;

  const int hw = blockIdx.x + (blockIdx.y << 3);
  const int xcd = hw & 7, sq = hw >> 3;
  const int pan = sq & 3, xb = sq >> 2;
  const int prow = pan * 8 + xcd;

  const int t = threadIdx.x;
  const int lane = t & 63;
  const int wv = t >> 6;
  const int wm = wv >> 1, wn = wv & 1;
  const int g = lane >> 4, lr = lane & 15;
  const int bm = prow << 7, bn = xb << 7;
  const int K = DMODEL;

  f32x4 acc[4][4] = {};
  for (int kt = 0; kt < K / 64; ++kt) {
    const int k0 = kt << 6;
    __syncthreads();
#pragma unroll
    for (int i = 0; i < 4; ++i) {
      int c = t + (i << 8);
      int row = c >> 3, col8 = c & 7;
      int c8s = col8 ^ (row & 7);
      int grow = bm + row;
      int b = grow >> 11, s = grow & (S_LEN - 1);
      int k = k0 + c8s * 8;
      int h = k >> 6, dk = k & (DKH - 1);
      gl2lds16(&Ao[(((size_t)(b * NHEAD + h)) * S_LEN + s) * DKH + dk], &As[c * 8]);
      gl2lds16(&Wb[(size_t)(bn + row) * K + k0 + c8s * 8], &Bs[c * 8]);
    }
    __syncthreads();
    bf16x8 af[2][4], bf[2][4];
#pragma unroll
    for (int kc = 0; kc < 2; ++kc)
#pragma unroll
      for (int f = 0; f < 4; ++f) {
        af[kc][f] = *(const bf16x8*)&As[SWZ(wm * 64 + f * 16 + lr, kc * 4 + g)];
        bf[kc][f] = *(const bf16x8*)&Bs[SWZ(wn * 64 + f * 16 + lr, kc * 4 + g)];
      }
#pragma unroll
    for (int kc = 0; kc < 2; ++kc)
#pragma unroll
      for (int fm = 0; fm < 4; ++fm)
#pragma unroll
        for (int fn = 0; fn < 4; ++fn)
          acc[fm][fn] = mfma16x16(af[kc][fm], bf[kc][fn], acc[fm][fn]);
  }
#pragma unroll
  for (int fm = 0; fm < 4; ++fm)
#pragma unroll
    for (int fn = 0; fn < 4; ++fn) {
      const int col = bn + wn * 64 + fn * 16 + lr;
      const float bb = bias[col];
#pragma unroll
      for (int r = 0; r < 4; ++r) {
        const int row = bm + wm * 64 + fm * 16 + g * 4 + r;
        Out[(size_t)row * DMODEL + col] = acc[fm][fn][r] + bb;
      }
    }
}

// ================= old R4 GEMM path (fallback if ws_size < 40 MB) =============
template<bool AF32, int OMODE>
__global__ __launch_bounds__(256)
void gemm64(const void* __restrict__ Ap, const float* __restrict__ Bt,
            const float* __restrict__ bias, void* __restrict__ outp,
            int M, int N, int K)
{
  __shared__ u16 As[64 * LDT];
  __shared__ u16 Bs[64 * LDT];
  const int t = threadIdx.x;
  const int lane = t & 63;
  const int wv = t >> 6;
  const int wm = wv >> 1, wn = wv & 1;
  const int g = lane >> 4, lr = lane & 15;
  const int bm = blockIdx.y << 6, bn = blockIdx.x << 6;

  f32x4 acc[2][2] = {};
  const int nk = K >> 6;
  for (int kt = 0; kt < nk; ++kt) {
    const int k0 = kt << 6;
    __syncthreads();
#pragma unroll
    for (int i = 0; i < 2; ++i) {
      int c = t + (i << 8);
      int row = c >> 3, col = (c & 7) << 3;
      short8 av;
      if (AF32) {
        const float* Af = (const float*)Ap;
        const float4* pa = (const float4*)&Af[(size_t)(bm + row) * K + k0 + col];
        av = pack8(pa[0], pa[1]);
      } else {
        av = *(const short8*)&((const u16*)Ap)[(size_t)(bm + row) * K + k0 + col];
      }
      *(short8*)&As[row * LDT + col] = av;
      const float4* pb = (const float4*)&Bt[(size_t)(bn + row) * K + k0 + col];
      *(short8*)&Bs[row * LDT + col] = pack8(pb[0], pb[1]);
    }
    __syncthreads();
    bf16x8 af[2][2], bfr[2][2];
#pragma unroll
    for (int kc = 0; kc < 2; ++kc) {
#pragma unroll
      for (int fm = 0; fm < 2; ++fm)
        af[kc][fm] = *(const bf16x8*)&As[(wm * 32 + fm * 16 + lr) * LDT + kc * 32 + g * 8];
#pragma unroll
      for (int fn = 0; fn < 2; ++fn)
        bfr[kc][fn] = *(const bf16x8*)&Bs[(wn * 32 + fn * 16 + lr) * LDT + kc * 32 + g * 8];
    }
#pragma unroll
    for (int kc = 0; kc < 2; ++kc)
#pragma unroll
      for (int fm = 0; fm < 2; ++fm)
#pragma unroll
        for (int fn = 0; fn < 2; ++fn)
          acc[fm][fn] = mfma16x16(af[kc][fm], bfr[kc][fn], acc[fm][fn]);
  }
  if (OMODE == 2) {
    u16* TL = As;
    __syncthreads();
#pragma unroll
    for (int fm = 0; fm < 2; ++fm)
#pragma unroll
      for (int fn = 0; fn < 2; ++fn) {
        const int lc = wn * 32 + fn * 16 + lr;
        const float bb = bias[bn + lc];
#pragma unroll
        for (int r = 0; r < 4; ++r) {
          const int lrow = wm * 32 + fm * 16 + g * 4 + r;
          TL[lc * LDT + lrow] = f2bf(acc[fm][fn][r] + bb);
        }
      }
    __syncthreads();
    const int bh = (bm >> 11) * NHEAD + (bn >> 6);
    const int s0 = bm & (S_LEN - 1);
#pragma unroll
    for (int i = 0; i < 2; ++i) {
      int c = t + (i << 8);
      int dr = c >> 3, sc = (c & 7) << 3;
      short8 vv = *(const short8*)&TL[dr * LDT + sc];
      *(short8*)&((u16*)outp)[((size_t)bh * DKH + dr) * S_LEN + s0 + sc] = vv;
    }
  } else {
#pragma unroll
    for (int fm = 0; fm < 2; ++fm)
#pragma unroll
      for (int fn = 0; fn < 2; ++fn) {
        const int col = bn + wn * 32 + fn * 16 + lr;
        const float bb = bias[col];
#pragma unroll
        for (int r = 0; r < 4; ++r) {
          const int row = bm + wm * 32 + fm * 16 + g * 4 + r;
          float vv = acc[fm][fn][r] + bb;
          if (OMODE == 1) {
            int b = row >> 11, s = row & (S_LEN - 1);
            int h = col >> 6, dk = col & (DKH - 1);
            ((u16*)outp)[(((size_t)(b * NHEAD + h)) * S_LEN + s) * DKH + dk] = f2bf(vv);
          } else {
            ((float*)outp)[(size_t)row * N + col] = vv;
          }
        }
      }
  }
}

// Flash attention, causal, paired q-tiles {p, 31-p}. HS: Ao head-split layout.
// Swapped QK^T: S[kv][q] so q-row is in-lane; scalar m,l; defer-rescale.
template<bool HS>
__global__ __launch_bounds__(256)
void attn_fwd(const u16* __restrict__ Qh, const u16* __restrict__ Kh,
              const u16* __restrict__ Vtg, u16* __restrict__ Ao)
{
  __shared__ u16 Ks[2][64 * LDT];
  __shared__ u16 Vs[2][64 * LDT];
  __shared__ u16 Ps[8][16 * LDT];
  const int t = threadIdx.x, lane = t & 63, w = t >> 6;
  const int g = lane >> 4, lr = lane & 15;
  const int bh = blockIdx.y;
  const int pA = blockIdx.x;
  const int tA = pA, tB = 31 - pA;
  const u16* Qb = Qh + (size_t)bh * S_LEN * DKH;
  const u16* Kb = Kh + (size_t)bh * S_LEN * DKH;
  const u16* Vb = Vtg + (size_t)bh * DKH * S_LEN;

  bf16x8 qfA[2], qfB[2];
#pragma unroll
  for (int kc = 0; kc < 2; ++kc) {
    qfA[kc] = *(const bf16x8*)&Qb[(size_t)(tA * 64 + w * 16 + lr) * DKH + kc * 32 + g * 8];
    qfB[kc] = *(const bf16x8*)&Qb[(size_t)(tB * 64 + w * 16 + lr) * DKH + kc * 32 + g * 8];
  }

  f32x4 oA[4] = {}, oB[4] = {};
  float mA = -1e30f, lA = 0.f, mB = -1e30f, lB = 0.f;

  const int r0 = t >> 3;
  const int c0 = (t & 7) << 3;
  short8 kr0, kr1, vr0, vr1;

  auto LOADT = [&](int kt) {
    const int kv0 = kt << 6;
    kr0 = *(const short8*)&Kb[(size_t)(kv0 + r0) * DKH + c0];
    kr1 = *(const short8*)&Kb[(size_t)(kv0 + r0 + 32) * DKH + c0];
    vr0 = *(const short8*)&Vb[(size_t)r0 * S_LEN + kv0 + c0];
    vr1 = *(const short8*)&Vb[(size_t)(r0 + 32) * S_LEN + kv0 + c0];
  };
  auto WRITET = [&](int b) {
    *(short8*)&Ks[b][r0 * LDT + c0] = kr0;
    *(short8*)&Ks[b][(r0 + 32) * LDT + c0] = kr1;
    *(short8*)&Vs[b][r0 * LDT + c0] = vr0;
    *(short8*)&Vs[b][(r0 + 32) * LDT + c0] = vr1;
  };

  auto COMPUTE = [&](int buf, const bf16x8* qf, f32x4* o, float& m, float& l,
                     int pslot, bool diag) {
    // S^T tile: S[kv][q] = mfma(K, Q). lane: kv = fk*16 + 4g + r, q = lr.
    f32x4 sf[4];
#pragma unroll
    for (int fk = 0; fk < 4; ++fk) {
      f32x4 a = {};
#pragma unroll
      for (int kc = 0; kc < 2; ++kc) {
        bf16x8 kf = *(const bf16x8*)&Ks[buf][(fk * 16 + lr) * LDT + kc * 32 + g * 8];
        a = mfma16x16(kf, qf[kc], a);
      }
      sf[fk] = a;
    }
    if (diag) {
#pragma unroll
      for (int fk = 0; fk < 4; ++fk)
#pragma unroll
        for (int r = 0; r < 4; ++r)
          if (fk * 16 + 4 * g + r > w * 16 + lr) sf[fk][r] = -1e30f;
    }
    // row max: 15 in-lane fmax + 2 cross-lane steps (lanes {lr,+16,+32,+48})
    float pm = fmaxf(fmaxf(sf[0][0], sf[0][1]), fmaxf(sf[0][2], sf[0][3]));
#pragma unroll
    for (int fk = 1; fk < 4; ++fk)
      pm = fmaxf(pm, fmaxf(fmaxf(sf[fk][0], sf[fk][1]), fmaxf(sf[fk][2], sf[fk][3])));
    pm = fmaxf(pm, __shfl_xor(pm, 16, 64));
    pm = fmaxf(pm, __shfl_xor(pm, 32, 64));
    // defer-rescale (T13): scale=1/8 -> raw threshold 64 bounds P by e^8
    float alpha = 1.0f;
    if (!__all(pm - m <= 64.0f)) {
      float mn = fmaxf(m, pm);
      alpha = __expf((m - mn) * 0.125f);
      m = mn;
#pragma unroll
      for (int r = 0; r < 4; ++r) {
        float ar = __shfl(alpha, 4 * g + r, 64);   // alpha of O-row 4g+r
#pragma unroll
        for (int d = 0; d < 4; ++d) o[d][r] *= ar;
      }
    }
    // p = exp((s-m)/8); pack 4 (contiguous kv) -> one b64 store per fk
    float rs = 0.f;
#pragma unroll
    for (int fk = 0; fk < 4; ++fk) {
      float p0 = __expf((sf[fk][0] - m) * 0.125f);
      float p1 = __expf((sf[fk][1] - m) * 0.125f);
      float p2 = __expf((sf[fk][2] - m) * 0.125f);
      float p3 = __expf((sf[fk][3] - m) * 0.125f);
      rs += (p0 + p1) + (p2 + p3);
      short4v pk;
      pk[0] = (short)f2bf(p0); pk[1] = (short)f2bf(p1);
      pk[2] = (short)f2bf(p2); pk[3] = (short)f2bf(p3);
      *(short4v*)&Ps[pslot][lr * LDT + fk * 16 + 4 * g] = pk;
    }
    rs += __shfl_xor(rs, 16, 64);
    rs += __shfl_xor(rs, 32, 64);
    l = l * alpha + rs;          // alpha==1 on deferred tiles
    // O += P V   (P as A-frag: row=q=lr; V^T as B: col=d)
#pragma unroll
    for (int kc = 0; kc < 2; ++kc) {
      bf16x8 pf = *(const bf16x8*)&Ps[pslot][lr * LDT + kc * 32 + g * 8];
#pragma unroll
      for (int df = 0; df < 4; ++df) {
        bf16x8 vf = *(const bf16x8*)&Vs[buf][(df * 16 + lr) * LDT + kc * 32 + g * 8];
        o[df] = mfma16x16(pf, vf, o[df]);
      }
    }
  };

  const int nt = tB + 1;
  LOADT(0);
  WRITET(0);
  for (int kt = 0; kt < nt; ++kt) {
    const int cur = kt & 1;
    const bool more = (kt + 1 < nt);
    if (more) LOADT(kt + 1);
    __syncthreads();
    if (kt <= tA) COMPUTE(cur, qfA, oA, mA, lA, w, kt == tA);
    COMPUTE(cur, qfB, oB, mB, lB, 4 + w, kt == tB);
    if (more) WRITET(cur ^ 1);
  }

  // broadcast l to O-row owners, write out
  float iA[4], iB[4];
#pragma unroll
  for (int r = 0; r < 4; ++r) {
    iA[r] = __builtin_amdgcn_rcpf(__shfl(lA, 4 * g + r, 64));
    iB[r] = __builtin_amdgcn_rcpf(__shfl(lB, 4 * g + r, 64));
  }
  const int b = bh >> 4, h = bh & (NHEAD - 1);
#pragma unroll
  for (int df = 0; df < 4; ++df)
#pragma unroll
    for (int r = 0; r < 4; ++r) {
      const int d = df * 16 + lr;
      const int qa = tA * 64 + w * 16 + g * 4 + r;
      const int qb2 = tB * 64 + w * 16 + g * 4 + r;
      if (HS) {
        Ao[((size_t)bh * S_LEN + qa) * DKH + d] = f2bf(oA[df][r] * iA[r]);
        Ao[((size_t)bh * S_LEN + qb2) * DKH + d] = f2bf(oB[df][r] * iB[r]);
      } else {
        Ao[((size_t)(b * S_LEN + qa)) * DMODEL + h * DKH + d] = f2bf(oA[df][r] * iA[r]);
        Ao[((size_t)(b * S_LEN + qb2)) * DMODEL + h * DKH + d] = f2bf(oB[df][r] * iB[r]);
      }
    }
}

extern "C" void kernel_launch(void* const* d_in, const int* in_sizes, int n_in,
                              void* d_out, int out_size, void* d_ws, size_t ws_size,
                              hipStream_t stream)
{
  (void)in_sizes; (void)n_in; (void)out_size;
  const float* q  = (const float*)d_in[0];
  const float* k  = (const float*)d_in[1];
  const float* v  = (const float*)d_in[2];
  const float* Wq = (const float*)d_in[4];
  const float* bq = (const float*)d_in[5];
  const float* Wk = (const float*)d_in[6];
  const float* bk = (const float*)d_in[7];
  const float* Wv = (const float*)d_in[8];
  const float* bv = (const float*)d_in[9];
  const float* Wo = (const float*)d_in[10];
  const float* bo = (const float*)d_in[11];

  char* ws = (char*)d_ws;
  const size_t MB = 1024 * 1024;

  if (ws_size >= 40 * MB) {
    u16* Wqb = (u16*)(ws);
    u16* Wkb = (u16*)(ws + 2 * MB);
    u16* Wvb = (u16*)(ws + 4 * MB);
    u16* Wob = (u16*)(ws + 6 * MB);
    u16* Qh  = (u16*)(ws + 8 * MB);
    u16* Kh  = (u16*)(ws + 16 * MB);
    u16* Vt  = (u16*)(ws + 24 * MB);
    u16* Ao  = (u16*)(ws + 32 * MB);

    conv_w<<<dim3(512, 4), 256, 0, stream>>>(Wq, Wk, Wv, Wo, Wqb, Wkb, Wvb, Wob);
    proj_gemm<<<dim3(8, 32, 3), 256, 0, stream>>>(q, k, v, Wqb, Wkb, Wvb,
                                                  bq, bk, bv, Qh, Kh, Vt);
    attn_fwd<true><<<dim3(16, 2 * NHEAD), 256, 0, stream>>>(Qh, Kh, Vt, Ao);
    out_gemm<<<dim3(8, 32), 256, 0, stream>>>(Ao, Wob, bo, (float*)d_out);
  } else {
    u16* Qh = (u16*)(ws);
    u16* Kh = (u16*)(ws + 8 * MB);
    u16* Vt = (u16*)(ws + 16 * MB);
    u16* Ao = (u16*)(ws + 24 * MB);
    const int M = 2 * S_LEN, N = DMODEL, K = DMODEL;
    dim3 gg(N / 64, M / 64), bb(256);
    gemm64<true, 1><<<gg, bb, 0, stream>>>(q, Wq, bq, Qh, M, N, K);
    gemm64<true, 1><<<gg, bb, 0, stream>>>(k, Wk, bk, Kh, M, N, K);
    gemm64<true, 2><<<gg, bb, 0, stream>>>(v, Wv, bv, Vt, M, N, K);
    attn_fwd<false><<<dim3(16, 2 * NHEAD), bb, 0, stream>>>(Qh, Kh, Vt, Ao);
    gemm64<false, 0><<<gg, bb, 0, stream>>>(Ao, Wo, bo, d_out, M, N, K);
  }
}

// Round 8
// 131.712 us; speedup vs baseline: 2.4306x; 1.0622x over previous
//
#include <hip/hip_runtime.h>

// MHA forward: B=2, S=2048, D=1024, H=16, DK=64. fp32 in/out, bf16 MFMA compute.
// R8: pipelined GEMM staging (attention unchanged from R7).
//  - proj_gemm: issue-early dbuf. Next-tile A global->reg loads + B gl_lds
//    issued BEFORE compute; post-compute __syncthreads drains them (latency
//    hidden under 16 ds_read + 32 MFMA). A single LDS buffer (rewritten in
//    the inter-sync window), B double-buffered. 48 KB LDS -> 3 blocks/CU.
//  - out_gemm: both operands gl_lds, double-buffered, stage-before-compute,
//    one __syncthreads per K-step.

#define S_LEN 2048
#define NHEAD 16
#define DMODEL 1024
#define DKH 64
#define LDT 88   // padded LDS row stride for 64-wide tiles (attn + fallback)

typedef unsigned short u16;
typedef __attribute__((ext_vector_type(4))) short short4v;
typedef __attribute__((ext_vector_type(8))) short short8;
typedef __attribute__((ext_vector_type(8))) __bf16 bf16x8;
typedef __attribute__((ext_vector_type(4))) float f32x4;

__device__ inline u16 f2bf(float f) {
  return __builtin_bit_cast(u16, (__bf16)f);   // v_cvt RNE
}

__device__ inline f32x4 mfma16x16(bf16x8 a, bf16x8 b, f32x4 c) {
  return __builtin_amdgcn_mfma_f32_16x16x32_bf16(a, b, c, 0, 0, 0);
}

__device__ inline short8 pack8(float4 a, float4 b) {
  short8 r;
  r[0] = (short)f2bf(a.x); r[1] = (short)f2bf(a.y);
  r[2] = (short)f2bf(a.z); r[3] = (short)f2bf(a.w);
  r[4] = (short)f2bf(b.x); r[5] = (short)f2bf(b.y);
  r[6] = (short)f2bf(b.z); r[7] = (short)f2bf(b.w);
  return r;
}

typedef const __attribute__((address_space(1))) unsigned GU32;
typedef __attribute__((address_space(3))) unsigned LU32;
__device__ inline void gl2lds16(const void* g, void* l) {
  __builtin_amdgcn_global_load_lds((GU32*)g, (LU32*)l, 16, 0, 0);
}

// swizzled elem-offset into a [rows][64] bf16 tile; col8 = 16B-slot index 0..7
#define SWZ(row, col8) (((row) * 8 + ((col8) ^ ((row) & 7))) * 8)

// ---------- weight conversion: 4x [1024x1024] f32 -> bf16 ----------
__global__ __launch_bounds__(256)
void conv_w(const float* __restrict__ w0, const float* __restrict__ w1,
            const float* __restrict__ w2, const float* __restrict__ w3,
            u16* __restrict__ o0, u16* __restrict__ o1,
            u16* __restrict__ o2, u16* __restrict__ o3)
{
  const int z = blockIdx.y;
  const float* s = z == 0 ? w0 : z == 1 ? w1 : z == 2 ? w2 : w3;
  u16* d = z == 0 ? o0 : z == 1 ? o1 : z == 2 ? o2 : o3;
  const int i = (blockIdx.x * 256 + threadIdx.x) * 8;
  float4 a = *(const float4*)&s[i];
  float4 b = *(const float4*)&s[i + 4];
  *(short8*)&d[i] = pack8(a, b);
}

// ---------- batched projection GEMMs (q,k,v) x (Wq,Wk,Wv), 128x128, BK=64 ----
__global__ __launch_bounds__(256)
void proj_gemm(const float* __restrict__ Aq, const float* __restrict__ Akk,
               const float* __restrict__ Av,
               const u16* __restrict__ Bq, const u16* __restrict__ Bk,
               const u16* __restrict__ Bv,
               const float* __restrict__ cq, const float* __restrict__ ck,
               const float* __restrict__ cv,
               u16* __restrict__ Oq, u16* __restrict__ Ok, u16* __restrict__ Ov)
{
  __shared__ u16 SM[3 * 128 * 64];           // [A][B0][B1] = 48 KB
  u16* As = SM;
  u16* Bs0 = SM + 8192;
  u16* Bs1 = SM + 16384;

  const int hw = blockIdx.x + (blockIdx.y << 3) + (blockIdx.z << 8);  // 0..767
  const int xcd = hw & 7, sq = hw >> 3;
  const int pan = sq % 12, xb = sq / 12;
  const int p = pan * 8 + xcd;
  const int zz = p >> 5, py = p & 31;

  const float* Af = zz == 0 ? Aq : zz == 1 ? Akk : Av;
  const u16* Wb = zz == 0 ? Bq : zz == 1 ? Bk : Bv;
  const float* bias = zz == 0 ? cq : zz == 1 ? ck : cv;

  const int t = threadIdx.x;
  const int lane = t & 63;
  const int wv = t >> 6;
  const int wm = wv >> 1, wn = wv & 1;
  const int g = lane >> 4, lr = lane & 15;
  const int bm = py << 7, bn = xb << 7;
  const int K = DMODEL;

  float4 ax[4], ay[4];                        // in-flight A tile (32 VGPR)
  auto ALOAD = [&](int kt) {
    const int k0 = kt << 6;
#pragma unroll
    for (int i = 0; i < 4; ++i) {
      int c = t + (i << 8);
      int row = c >> 3, col8 = c & 7;
      const float* src = &Af[(size_t)(bm + row) * K + k0 + col8 * 8];
      ax[i] = *(const float4*)src;
      ay[i] = *(const float4*)(src + 4);
    }
  };
  auto AWRITE = [&]() {
#pragma unroll
    for (int i = 0; i < 4; ++i) {
      int c = t + (i << 8);
      int row = c >> 3, col8 = c & 7;
      *(short8*)&As[SWZ(row, col8)] = pack8(ax[i], ay[i]);
    }
  };
  auto BSTAGE = [&](u16* buf, int kt) {
    const int k0 = kt << 6;
#pragma unroll
    for (int i = 0; i < 4; ++i) {
      int c = t + (i << 8);
      int row = c >> 3, col8 = c & 7;
      int c8s = col8 ^ (row & 7);
      gl2lds16(&Wb[(size_t)(bn + row) * K + k0 + c8s * 8], &buf[c * 8]);
    }
  };

  f32x4 acc[4][4] = {};
  ALOAD(0);
  BSTAGE(Bs0, 0);
  AWRITE();
  __syncthreads();
  for (int kt = 0; kt < 16; ++kt) {
    u16* Bcur = (kt & 1) ? Bs1 : Bs0;
    u16* Bnxt = (kt & 1) ? Bs0 : Bs1;
    const bool more = (kt + 1 < 16);
    if (more) { ALOAD(kt + 1); BSTAGE(Bnxt, kt + 1); }   // issue-early
    bf16x8 af[2][4], bf[2][4];
#pragma unroll
    for (int kc = 0; kc < 2; ++kc)
#pragma unroll
      for (int f = 0; f < 4; ++f) {
        af[kc][f] = *(const bf16x8*)&As[SWZ(wm * 64 + f * 16 + lr, kc * 4 + g)];
        bf[kc][f] = *(const bf16x8*)&Bcur[SWZ(wn * 64 + f * 16 + lr, kc * 4 + g)];
      }
#pragma unroll
    for (int kc = 0; kc < 2; ++kc)
#pragma unroll
      for (int fm = 0; fm < 4; ++fm)
#pragma unroll
        for (int fn = 0; fn < 4; ++fn)
          acc[fm][fn] = mfma16x16(af[kc][fm], bf[kc][fn], acc[fm][fn]);
    __syncthreads();                 // drains issued loads; all waves done reading
    if (more) {
      AWRITE();                      // rewrite single A buffer (cheap window)
      __syncthreads();               // A writes visible before next compute
    }
  }

  if (zz == 2) {
    u16* TL = SM;
    const int b = bm >> 11, s0 = bm & (S_LEN - 1), h0 = bn >> 6;
#pragma unroll
    for (int hh = 0; hh < 2; ++hh) {
      __syncthreads();
      if (wn == hh) {
#pragma unroll
        for (int fm = 0; fm < 4; ++fm)
#pragma unroll
          for (int fn = 0; fn < 4; ++fn) {
            const int lch = fn * 16 + lr;
            const float bb = bias[bn + hh * 64 + lch];
#pragma unroll
            for (int r = 0; r < 4; ++r)
              TL[lch * 132 + wm * 64 + fm * 16 + g * 4 + r] = f2bf(acc[fm][fn][r] + bb);
          }
      }
      __syncthreads();
#pragma unroll
      for (int i = 0; i < 4; ++i) {
        int c = t + (i << 8);
        int dk = c >> 4, sc = (c & 15) << 3;
        short8 vv = *(const short8*)&TL[dk * 132 + sc];
        *(short8*)&Ov[(((size_t)(b * NHEAD + h0 + hh)) * DKH + dk) * S_LEN + s0 + sc] = vv;
      }
    }
  } else {
    u16* Out = zz == 0 ? Oq : Ok;
#pragma unroll
    for (int fm = 0; fm < 4; ++fm)
#pragma unroll
      for (int fn = 0; fn < 4; ++fn) {
        const int col = bn + wn * 64 + fn * 16 + lr;
        const int h = col >> 6, dk = col & (DKH - 1);
        const float bb = bias[col];
#pragma unroll
        for (int r = 0; r < 4; ++r) {
          const int row = bm + wm * 64 + fm * 16 + g * 4 + r;
          const int b = row >> 11, s = row & (S_LEN - 1);
          Out[(((size_t)(b * NHEAD + h)) * S_LEN + s) * DKH + dk] = f2bf(acc[fm][fn][r] + bb);
        }
      }
  }
}

// ---------- O-projection: Ao(head-split bf16) @ Wo^T + bo -> f32 out ----------
__global__ __launch_bounds__(256)
void out_gemm(const u16* __restrict__ Ao, const u16* __restrict__ Wb,
              const float* __restrict__ bias, float* __restrict__ Out)
{
  __shared__ u16 SM[4 * 128 * 64];            // [A0][A1][B0][B1] = 64 KB
  const int hw = blockIdx.x + (blockIdx.y << 3);
  const int xcd = hw & 7, sq = hw >> 3;
  const int pan = sq & 3, xb = sq >> 2;
  const int prow = pan * 8 + xcd;

  const int t = threadIdx.x;
  const int lane = t & 63;
  const int wv = t >> 6;
  const int wm = wv >> 1, wn = wv & 1;
  const int g = lane >> 4, lr = lane & 15;
  const int bm = prow << 7, bn = xb << 7;
  const int K = DMODEL;

  auto STAGE = [&](int buf, int kt) {
    const int k0 = kt << 6;
    u16* Asb = SM + buf * 8192;
    u16* Bsb = SM + 16384 + buf * 8192;
#pragma unroll
    for (int i = 0; i < 4; ++i) {
      int c = t + (i << 8);
      int row = c >> 3, col8 = c & 7;
      int c8s = col8 ^ (row & 7);
      int grow = bm + row;
      int b = grow >> 11, s = grow & (S_LEN - 1);
      int k = k0 + c8s * 8;
      int h = k >> 6, dk = k & (DKH - 1);
      gl2lds16(&Ao[(((size_t)(b * NHEAD + h)) * S_LEN + s) * DKH + dk], &Asb[c * 8]);
      gl2lds16(&Wb[(size_t)(bn + row) * K + k0 + c8s * 8], &Bsb[c * 8]);
    }
  };

  f32x4 acc[4][4] = {};
  STAGE(0, 0);
  __syncthreads();
  for (int kt = 0; kt < 16; ++kt) {
    const int cur = kt & 1;
    if (kt + 1 < 16) STAGE(cur ^ 1, kt + 1);   // issue-early
    u16* Asb = SM + cur * 8192;
    u16* Bsb = SM + 16384 + cur * 8192;
    bf16x8 af[2][4], bf[2][4];
#pragma unroll
    for (int kc = 0; kc < 2; ++kc)
#pragma unroll
      for (int f = 0; f < 4; ++f) {
        af[kc][f] = *(const bf16x8*)&Asb[SWZ(wm * 64 + f * 16 + lr, kc * 4 + g)];
        bf[kc][f] = *(const bf16x8*)&Bsb[SWZ(wn * 64 + f * 16 + lr, kc * 4 + g)];
      }
#pragma unroll
    for (int kc = 0; kc < 2; ++kc)
#pragma unroll
      for (int fm = 0; fm < 4; ++fm)
#pragma unroll
        for (int fn = 0; fn < 4; ++fn)
          acc[fm][fn] = mfma16x16(af[kc][fm], bf[kc][fn], acc[fm][fn]);
    __syncthreads();                 // drains this iter's staged loads
  }
#pragma unroll
  for (int fm = 0; fm < 4; ++fm)
#pragma unroll
    for (int fn = 0; fn < 4; ++fn) {
      const int col = bn + wn * 64 + fn * 16 + lr;
      const float bb = bias[col];
#pragma unroll
      for (int r = 0; r < 4; ++r) {
        const int row = bm + wm * 64 + fm * 16 + g * 4 + r;
        Out[(size_t)row * DMODEL + col] = acc[fm][fn][r] + bb;
      }
    }
}

// ================= old R4 GEMM path (fallback if ws_size < 40 MB) =============
template<bool AF32, int OMODE>
__global__ __launch_bounds__(256)
void gemm64(const void* __restrict__ Ap, const float* __restrict__ Bt,
            const float* __restrict__ bias, void* __restrict__ outp,
            int M, int N, int K)
{
  __shared__ u16 As[64 * LDT];
  __shared__ u16 Bs[64 * LDT];
  const int t = threadIdx.x;
  const int lane = t & 63;
  const int wv = t >> 6;
  const int wm = wv >> 1, wn = wv & 1;
  const int g = lane >> 4, lr = lane & 15;
  const int bm = blockIdx.y << 6, bn = blockIdx.x << 6;

  f32x4 acc[2][2] = {};
  const int nk = K >> 6;
  for (int kt = 0; kt < nk; ++kt) {
    const int k0 = kt << 6;
    __syncthreads();
#pragma unroll
    for (int i = 0; i < 2; ++i) {
      int c = t + (i << 8);
      int row = c >> 3, col = (c & 7) << 3;
      short8 av;
      if (AF32) {
        const float* Af = (const float*)Ap;
        const float4* pa = (const float4*)&Af[(size_t)(bm + row) * K + k0 + col];
        av = pack8(pa[0], pa[1]);
      } else {
        av = *(const short8*)&((const u16*)Ap)[(size_t)(bm + row) * K + k0 + col];
      }
      *(short8*)&As[row * LDT + col] = av;
      const float4* pb = (const float4*)&Bt[(size_t)(bn + row) * K + k0 + col];
      *(short8*)&Bs[row * LDT + col] = pack8(pb[0], pb[1]);
    }
    __syncthreads();
    bf16x8 af[2][2], bfr[2][2];
#pragma unroll
    for (int kc = 0; kc < 2; ++kc) {
#pragma unroll
      for (int fm = 0; fm < 2; ++fm)
        af[kc][fm] = *(const bf16x8*)&As[(wm * 32 + fm * 16 + lr) * LDT + kc * 32 + g * 8];
#pragma unroll
      for (int fn = 0; fn < 2; ++fn)
        bfr[kc][fn] = *(const bf16x8*)&Bs[(wn * 32 + fn * 16 + lr) * LDT + kc * 32 + g * 8];
    }
#pragma unroll
    for (int kc = 0; kc < 2; ++kc)
#pragma unroll
      for (int fm = 0; fm < 2; ++fm)
#pragma unroll
        for (int fn = 0; fn < 2; ++fn)
          acc[fm][fn] = mfma16x16(af[kc][fm], bfr[kc][fn], acc[fm][fn]);
  }
  if (OMODE == 2) {
    u16* TL = As;
    __syncthreads();
#pragma unroll
    for (int fm = 0; fm < 2; ++fm)
#pragma unroll
      for (int fn = 0; fn < 2; ++fn) {
        const int lc = wn * 32 + fn * 16 + lr;
        const float bb = bias[bn + lc];
#pragma unroll
        for (int r = 0; r < 4; ++r) {
          const int lrow = wm * 32 + fm * 16 + g * 4 + r;
          TL[lc * LDT + lrow] = f2bf(acc[fm][fn][r] + bb);
        }
      }
    __syncthreads();
    const int bh = (bm >> 11) * NHEAD + (bn >> 6);
    const int s0 = bm & (S_LEN - 1);
#pragma unroll
    for (int i = 0; i < 2; ++i) {
      int c = t + (i << 8);
      int dr = c >> 3, sc = (c & 7) << 3;
      short8 vv = *(const short8*)&TL[dr * LDT + sc];
      *(short8*)&((u16*)outp)[((size_t)bh * DKH + dr) * S_LEN + s0 + sc] = vv;
    }
  } else {
#pragma unroll
    for (int fm = 0; fm < 2; ++fm)
#pragma unroll
      for (int fn = 0; fn < 2; ++fn) {
        const int col = bn + wn * 32 + fn * 16 + lr;
        const float bb = bias[col];
#pragma unroll
        for (int r = 0; r < 4; ++r) {
          const int row = bm + wm * 32 + fm * 16 + g * 4 + r;
          float vv = acc[fm][fn][r] + bb;
          if (OMODE == 1) {
            int b = row >> 11, s = row & (S_LEN - 1);
            int h = col >> 6, dk = col & (DKH - 1);
            ((u16*)outp)[(((size_t)(b * NHEAD + h)) * S_LEN + s) * DKH + dk] = f2bf(vv);
          } else {
            ((float*)outp)[(size_t)row * N + col] = vv;
          }
        }
      }
  }
}

// Flash attention, causal, paired q-tiles {p, 31-p}. HS: Ao head-split layout.
// Swapped QK^T: S[kv][q] so q-row is in-lane; scalar m,l; defer-rescale.
template<bool HS>
__global__ __launch_bounds__(256)
void attn_fwd(const u16* __restrict__ Qh, const u16* __restrict__ Kh,
              const u16* __restrict__ Vtg, u16* __restrict__ Ao)
{
  __shared__ u16 Ks[2][64 * LDT];
  __shared__ u16 Vs[2][64 * LDT];
  __shared__ u16 Ps[8][16 * LDT];
  const int t = threadIdx.x, lane = t & 63, w = t >> 6;
  const int g = lane >> 4, lr = lane & 15;
  const int bh = blockIdx.y;
  const int pA = blockIdx.x;
  const int tA = pA, tB = 31 - pA;
  const u16* Qb = Qh + (size_t)bh * S_LEN * DKH;
  const u16* Kb = Kh + (size_t)bh * S_LEN * DKH;
  const u16* Vb = Vtg + (size_t)bh * DKH * S_LEN;

  bf16x8 qfA[2], qfB[2];
#pragma unroll
  for (int kc = 0; kc < 2; ++kc) {
    qfA[kc] = *(const bf16x8*)&Qb[(size_t)(tA * 64 + w * 16 + lr) * DKH + kc * 32 + g * 8];
    qfB[kc] = *(const bf16x8*)&Qb[(size_t)(tB * 64 + w * 16 + lr) * DKH + kc * 32 + g * 8];
  }

  f32x4 oA[4] = {}, oB[4] = {};
  float mA = -1e30f, lA = 0.f, mB = -1e30f, lB = 0.f;

  const int r0 = t >> 3;
  const int c0 = (t & 7) << 3;
  short8 kr0, kr1, vr0, vr1;

  auto LOADT = [&](int kt) {
    const int kv0 = kt << 6;
    kr0 = *(const short8*)&Kb[(size_t)(kv0 + r0) * DKH + c0];
    kr1 = *(const short8*)&Kb[(size_t)(kv0 + r0 + 32) * DKH + c0];
    vr0 = *(const short8*)&Vb[(size_t)r0 * S_LEN + kv0 + c0];
    vr1 = *(const short8*)&Vb[(size_t)(r0 + 32) * S_LEN + kv0 + c0];
  };
  auto WRITET = [&](int b) {
    *(short8*)&Ks[b][r0 * LDT + c0] = kr0;
    *(short8*)&Ks[b][(r0 + 32) * LDT + c0] = kr1;
    *(short8*)&Vs[b][r0 * LDT + c0] = vr0;
    *(short8*)&Vs[b][(r0 + 32) * LDT + c0] = vr1;
  };

  auto COMPUTE = [&](int buf, const bf16x8* qf, f32x4* o, float& m, float& l,
                     int pslot, bool diag) {
    f32x4 sf[4];
#pragma unroll
    for (int fk = 0; fk < 4; ++fk) {
      f32x4 a = {};
#pragma unroll
      for (int kc = 0; kc < 2; ++kc) {
        bf16x8 kf = *(const bf16x8*)&Ks[buf][(fk * 16 + lr) * LDT + kc * 32 + g * 8];
        a = mfma16x16(kf, qf[kc], a);
      }
      sf[fk] = a;
    }
    if (diag) {
#pragma unroll
      for (int fk = 0; fk < 4; ++fk)
#pragma unroll
        for (int r = 0; r < 4; ++r)
          if (fk * 16 + 4 * g + r > w * 16 + lr) sf[fk][r] = -1e30f;
    }
    float pm = fmaxf(fmaxf(sf[0][0], sf[0][1]), fmaxf(sf[0][2], sf[0][3]));
#pragma unroll
    for (int fk = 1; fk < 4; ++fk)
      pm = fmaxf(pm, fmaxf(fmaxf(sf[fk][0], sf[fk][1]), fmaxf(sf[fk][2], sf[fk][3])));
    pm = fmaxf(pm, __shfl_xor(pm, 16, 64));
    pm = fmaxf(pm, __shfl_xor(pm, 32, 64));
    float alpha = 1.0f;
    if (!__all(pm - m <= 64.0f)) {
      float mn = fmaxf(m, pm);
      alpha = __expf((m - mn) * 0.125f);
      m = mn;
#pragma unroll
      for (int r = 0; r < 4; ++r) {
        float ar = __shfl(alpha, 4 * g + r, 64);
#pragma unroll
        for (int d = 0; d < 4; ++d) o[d][r] *= ar;
      }
    }
    float rs = 0.f;
#pragma unroll
    for (int fk = 0; fk < 4; ++fk) {
      float p0 = __expf((sf[fk][0] - m) * 0.125f);
      float p1 = __expf((sf[fk][1] - m) * 0.125f);
      float p2 = __expf((sf[fk][2] - m) * 0.125f);
      float p3 = __expf((sf[fk][3] - m) * 0.125f);
      rs += (p0 + p1) + (p2 + p3);
      short4v pk;
      pk[0] = (short)f2bf(p0); pk[1] = (short)f2bf(p1);
      pk[2] = (short)f2bf(p2); pk[3] = (short)f2bf(p3);
      *(short4v*)&Ps[pslot][lr * LDT + fk * 16 + 4 * g] = pk;
    }
    rs += __shfl_xor(rs, 16, 64);
    rs += __shfl_xor(rs, 32, 64);
    l = l * alpha + rs;
#pragma unroll
    for (int kc = 0; kc < 2; ++kc) {
      bf16x8 pf = *(const bf16x8*)&Ps[pslot][lr * LDT + kc * 32 + g * 8];
#pragma unroll
      for (int df = 0; df < 4; ++df) {
        bf16x8 vf = *(const bf16x8*)&Vs[buf][(df * 16 + lr) * LDT + kc * 32 + g * 8];
        o[df] = mfma16x16(pf, vf, o[df]);
      }
    }
  };

  const int nt = tB + 1;
  LOADT(0);
  WRITET(0);
  for (int kt = 0; kt < nt; ++kt) {
    const int cur = kt & 1;
    const bool more = (kt + 1 < nt);
    if (more) LOADT(kt + 1);
    __syncthreads();
    if (kt <= tA) COMPUTE(cur, qfA, oA, mA, lA, w, kt == tA);
    COMPUTE(cur, qfB, oB, mB, lB, 4 + w, kt == tB);
    if (more) WRITET(cur ^ 1);
  }

  float iA[4], iB[4];
#pragma unroll
  for (int r = 0; r < 4; ++r) {
    iA[r] = __builtin_amdgcn_rcpf(__shfl(lA, 4 * g + r, 64));
    iB[r] = __builtin_amdgcn_rcpf(__shfl(lB, 4 * g + r, 64));
  }
  const int b = bh >> 4, h = bh & (NHEAD - 1);
#pragma unroll
  for (int df = 0; df < 4; ++df)
#pragma unroll
    for (int r = 0; r < 4; ++r) {
      const int d = df * 16 + lr;
      const int qa = tA * 64 + w * 16 + g * 4 + r;
      const int qb2 = tB * 64 + w * 16 + g * 4 + r;
      if (HS) {
        Ao[((size_t)bh * S_LEN + qa) * DKH + d] = f2bf(oA[df][r] * iA[r]);
        Ao[((size_t)bh * S_LEN + qb2) * DKH + d] = f2bf(oB[df][r] * iB[r]);
      } else {
        Ao[((size_t)(b * S_LEN + qa)) * DMODEL + h * DKH + d] = f2bf(oA[df][r] * iA[r]);
        Ao[((size_t)(b * S_LEN + qb2)) * DMODEL + h * DKH + d] = f2bf(oB[df][r] * iB[r]);
      }
    }
}

extern "C" void kernel_launch(void* const* d_in, const int* in_sizes, int n_in,
                              void* d_out, int out_size, void* d_ws, size_t ws_size,
                              hipStream_t stream)
{
  (void)in_sizes; (void)n_in; (void)out_size;
  const float* q  = (const float*)d_in[0];
  const float* k  = (const float*)d_in[1];
  const float* v  = (const float*)d_in[2];
  const float* Wq = (const float*)d_in[4];
  const float* bq = (const float*)d_in[5];
  const float* Wk = (const float*)d_in[6];
  const float* bk = (const float*)d_in[7];
  const float* Wv = (const float*)d_in[8];
  const float* bv = (const float*)d_in[9];
  const float* Wo = (const float*)d_in[10];
  const float* bo = (const float*)d_in[11];

  char* ws = (char*)d_ws;
  const size_t MB = 1024 * 1024;

  if (ws_size >= 40 * MB) {
    u16* Wqb = (u16*)(ws);
    u16* Wkb = (u16*)(ws + 2 * MB);
    u16* Wvb = (u16*)(ws + 4 * MB);
    u16* Wob = (u16*)(ws + 6 * MB);
    u16* Qh  = (u16*)(ws + 8 * MB);
    u16* Kh  = (u16*)(ws + 16 * MB);
    u16* Vt  = (u16*)(ws + 24 * MB);
    u16* Ao  = (u16*)(ws + 32 * MB);

    conv_w<<<dim3(512, 4), 256, 0, stream>>>(Wq, Wk, Wv, Wo, Wqb, Wkb, Wvb, Wob);
    proj_gemm<<<dim3(8, 32, 3), 256, 0, stream>>>(q, k, v, Wqb, Wkb, Wvb,
                                                  bq, bk, bv, Qh, Kh, Vt);
    attn_fwd<true><<<dim3(16, 2 * NHEAD), 256, 0, stream>>>(Qh, Kh, Vt, Ao);
    out_gemm<<<dim3(8, 32), 256, 0, stream>>>(Ao, Wob, bo, (float*)d_out);
  } else {
    u16* Qh = (u16*)(ws);
    u16* Kh = (u16*)(ws + 8 * MB);
    u16* Vt = (u16*)(ws + 16 * MB);
    u16* Ao = (u16*)(ws + 24 * MB);
    const int M = 2 * S_LEN, N = DMODEL, K = DMODEL;
    dim3 gg(N / 64, M / 64), bb(256);
    gemm64<true, 1><<<gg, bb, 0, stream>>>(q, Wq, bq, Qh, M, N, K);
    gemm64<true, 1><<<gg, bb, 0, stream>>>(k, Wk, bk, Kh, M, N, K);
    gemm64<true, 2><<<gg, bb, 0, stream>>>(v, Wv, bv, Vt, M, N, K);
    attn_fwd<false><<<dim3(16, 2 * NHEAD), bb, 0, stream>>>(Qh, Kh, Vt, Ao);
    gemm64<false, 0><<<gg, bb, 0, stream>>>(Ao, Wo, bo, d_out, M, N, K);
  }
}

// Round 10
// 120.621 us; speedup vs baseline: 2.6540x; 1.0919x over previous
//
#include <hip/hip_runtime.h>

// MHA forward: B=2, S=2048, D=1024, H=16, DK=64. fp32 in/out, bf16 MFMA compute.
// R10 = R9 resubmit (container infra failure, no signal).
//  - conv_bf16 converts q,k,v AND the 4 weights to bf16 up front
//  - proj: A+B both global_load_lds double-buffered, 1 barrier/K-step
//  - Ao aliases qb (dead after proj): new tier needs 56 MB ws
//  - fallback (40-56 MB ws): R8 fp32-A reg-staged proj path

#define S_LEN 2048
#define NHEAD 16
#define DMODEL 1024
#define DKH 64
#define LDT 88   // padded LDS row stride for attn tiles

typedef unsigned short u16;
typedef __attribute__((ext_vector_type(4))) short short4v;
typedef __attribute__((ext_vector_type(8))) short short8;
typedef __attribute__((ext_vector_type(8))) __bf16 bf16x8;
typedef __attribute__((ext_vector_type(4))) float f32x4;

__device__ inline u16 f2bf(float f) {
  return __builtin_bit_cast(u16, (__bf16)f);   // v_cvt RNE
}

__device__ inline f32x4 mfma16x16(bf16x8 a, bf16x8 b, f32x4 c) {
  return __builtin_amdgcn_mfma_f32_16x16x32_bf16(a, b, c, 0, 0, 0);
}

__device__ inline short8 pack8(float4 a, float4 b) {
  short8 r;
  r[0] = (short)f2bf(a.x); r[1] = (short)f2bf(a.y);
  r[2] = (short)f2bf(a.z); r[3] = (short)f2bf(a.w);
  r[4] = (short)f2bf(b.x); r[5] = (short)f2bf(b.y);
  r[6] = (short)f2bf(b.z); r[7] = (short)f2bf(b.w);
  return r;
}

typedef const __attribute__((address_space(1))) unsigned GU32;
typedef __attribute__((address_space(3))) unsigned LU32;
__device__ inline void gl2lds16(const void* g, void* l) {
  __builtin_amdgcn_global_load_lds((GU32*)g, (LU32*)l, 16, 0, 0);
}

// swizzled elem-offset into a [rows][64] bf16 tile; col8 = 16B-slot index 0..7
#define SWZ(row, col8) (((row) * 8 + ((col8) ^ ((row) & 7))) * 8)

// ---------- f32 -> bf16 conversion: 4 weights (1M) + q,k,v (4M each) ----------
__global__ __launch_bounds__(256)
void conv_bf16(const float* __restrict__ w0, const float* __restrict__ w1,
               const float* __restrict__ w2, const float* __restrict__ w3,
               const float* __restrict__ aq, const float* __restrict__ ak,
               const float* __restrict__ av,
               u16* __restrict__ o0, u16* __restrict__ o1,
               u16* __restrict__ o2, u16* __restrict__ o3,
               u16* __restrict__ oq, u16* __restrict__ ok, u16* __restrict__ ov)
{
  const int y = blockIdx.y;
  const float* s; u16* d; int n;
  switch (y) {
    case 0: s = w0; d = o0; n = 1 << 20; break;
    case 1: s = w1; d = o1; n = 1 << 20; break;
    case 2: s = w2; d = o2; n = 1 << 20; break;
    case 3: s = w3; d = o3; n = 1 << 20; break;
    case 4: s = aq; d = oq; n = 1 << 22; break;
    case 5: s = ak; d = ok; n = 1 << 22; break;
    default: s = av; d = ov; n = 1 << 22; break;
  }
  const int i = (blockIdx.x * 256 + threadIdx.x) * 8;
  if (i >= n) return;
  float4 a = *(const float4*)&s[i];
  float4 b = *(const float4*)&s[i + 4];
  *(short8*)&d[i] = pack8(a, b);
}

// ---------- weight-only conversion (fallback tier) ----------
__global__ __launch_bounds__(256)
void conv_w(const float* __restrict__ w0, const float* __restrict__ w1,
            const float* __restrict__ w2, const float* __restrict__ w3,
            u16* __restrict__ o0, u16* __restrict__ o1,
            u16* __restrict__ o2, u16* __restrict__ o3)
{
  const int z = blockIdx.y;
  const float* s = z == 0 ? w0 : z == 1 ? w1 : z == 2 ? w2 : w3;
  u16* d = z == 0 ? o0 : z == 1 ? o1 : z == 2 ? o2 : o3;
  const int i = (blockIdx.x * 256 + threadIdx.x) * 8;
  float4 a = *(const float4*)&s[i];
  float4 b = *(const float4*)&s[i + 4];
  *(short8*)&d[i] = pack8(a, b);
}

// ---------- batched projection GEMMs, all-bf16, dbuf gl_lds (new tier) -------
// z=0,1 -> bf16 head-split [bh][s][dk]; z=2 -> bf16 transposed [bh][dk][s]
__global__ __launch_bounds__(256)
void proj_gemm_bf16(const u16* __restrict__ Aqb, const u16* __restrict__ Akb,
                    const u16* __restrict__ Avb,
                    const u16* __restrict__ Bq, const u16* __restrict__ Bk,
                    const u16* __restrict__ Bv,
                    const float* __restrict__ cq, const float* __restrict__ ck,
                    const float* __restrict__ cv,
                    u16* __restrict__ Oq, u16* __restrict__ Ok, u16* __restrict__ Ov)
{
  __shared__ u16 SM[4 * 8192];               // [A0][A1][B0][B1] = 64 KB

  const int hw = blockIdx.x + (blockIdx.y << 3) + (blockIdx.z << 8);  // 0..767
  const int xcd = hw & 7, sq = hw >> 3;
  const int pan = sq % 12, xb = sq / 12;
  const int p = pan * 8 + xcd;
  const int zz = p >> 5, py = p & 31;

  const u16* Ab = zz == 0 ? Aqb : zz == 1 ? Akb : Avb;
  const u16* Wb = zz == 0 ? Bq : zz == 1 ? Bk : Bv;
  const float* bias = zz == 0 ? cq : zz == 1 ? ck : cv;

  const int t = threadIdx.x;
  const int lane = t & 63;
  const int wv = t >> 6;
  const int wm = wv >> 1, wn = wv & 1;
  const int g = lane >> 4, lr = lane & 15;
  const int bm = py << 7, bn = xb << 7;
  const int K = DMODEL;

  auto STAGE = [&](int buf, int kt) {
    const int k0 = kt << 6;
    u16* Asb = SM + buf * 8192;
    u16* Bsb = SM + 16384 + buf * 8192;
#pragma unroll
    for (int i = 0; i < 4; ++i) {
      int c = t + (i << 8);
      int row = c >> 3, col8 = c & 7;
      int c8s = col8 ^ (row & 7);
      gl2lds16(&Ab[(size_t)(bm + row) * K + k0 + c8s * 8], &Asb[c * 8]);
      gl2lds16(&Wb[(size_t)(bn + row) * K + k0 + c8s * 8], &Bsb[c * 8]);
    }
  };

  f32x4 acc[4][4] = {};
  STAGE(0, 0);
  __syncthreads();
  for (int kt = 0; kt < 16; ++kt) {
    const int cur = kt & 1;
    if (kt + 1 < 16) STAGE(cur ^ 1, kt + 1);   // issue-early; drained by barrier
    u16* Asb = SM + cur * 8192;
    u16* Bsb = SM + 16384 + cur * 8192;
    bf16x8 af[2][4], bf[2][4];
#pragma unroll
    for (int kc = 0; kc < 2; ++kc)
#pragma unroll
      for (int f = 0; f < 4; ++f) {
        af[kc][f] = *(const bf16x8*)&Asb[SWZ(wm * 64 + f * 16 + lr, kc * 4 + g)];
        bf[kc][f] = *(const bf16x8*)&Bsb[SWZ(wn * 64 + f * 16 + lr, kc * 4 + g)];
      }
#pragma unroll
    for (int kc = 0; kc < 2; ++kc)
#pragma unroll
      for (int fm = 0; fm < 4; ++fm)
#pragma unroll
        for (int fn = 0; fn < 4; ++fn)
          acc[fm][fn] = mfma16x16(af[kc][fm], bf[kc][fn], acc[fm][fn]);
    __syncthreads();
  }

  if (zz == 2) {
    u16* TL = SM;
    const int b = bm >> 11, s0 = bm & (S_LEN - 1), h0 = bn >> 6;
#pragma unroll
    for (int hh = 0; hh < 2; ++hh) {
      __syncthreads();
      if (wn == hh) {
#pragma unroll
        for (int fm = 0; fm < 4; ++fm)
#pragma unroll
          for (int fn = 0; fn < 4; ++fn) {
            const int lch = fn * 16 + lr;
            const float bb = bias[bn + hh * 64 + lch];
#pragma unroll
            for (int r = 0; r < 4; ++r)
              TL[lch * 132 + wm * 64 + fm * 16 + g * 4 + r] = f2bf(acc[fm][fn][r] + bb);
          }
      }
      __syncthreads();
#pragma unroll
      for (int i = 0; i < 4; ++i) {
        int c = t + (i << 8);
        int dk = c >> 4, sc = (c & 15) << 3;
        short8 vv = *(const short8*)&TL[dk * 132 + sc];
        *(short8*)&Ov[(((size_t)(b * NHEAD + h0 + hh)) * DKH + dk) * S_LEN + s0 + sc] = vv;
      }
    }
  } else {
    u16* Out = zz == 0 ? Oq : Ok;
#pragma unroll
    for (int fm = 0; fm < 4; ++fm)
#pragma unroll
      for (int fn = 0; fn < 4; ++fn) {
        const int col = bn + wn * 64 + fn * 16 + lr;
        const int h = col >> 6, dk = col & (DKH - 1);
        const float bb = bias[col];
#pragma unroll
        for (int r = 0; r < 4; ++r) {
          const int row = bm + wm * 64 + fm * 16 + g * 4 + r;
          const int b = row >> 11, s = row & (S_LEN - 1);
          Out[(((size_t)(b * NHEAD + h)) * S_LEN + s) * DKH + dk] = f2bf(acc[fm][fn][r] + bb);
        }
      }
  }
}

// ---------- R8 proj (fp32 A reg-staged) — fallback tier ----------
__global__ __launch_bounds__(256)
void proj_gemm_f32(const float* __restrict__ Aq, const float* __restrict__ Akk,
                   const float* __restrict__ Av,
                   const u16* __restrict__ Bq, const u16* __restrict__ Bk,
                   const u16* __restrict__ Bv,
                   const float* __restrict__ cq, const float* __restrict__ ck,
                   const float* __restrict__ cv,
                   u16* __restrict__ Oq, u16* __restrict__ Ok, u16* __restrict__ Ov)
{
  __shared__ u16 SM[3 * 8192];
  u16* As = SM;
  u16* Bs0 = SM + 8192;
  u16* Bs1 = SM + 16384;

  const int hw = blockIdx.x + (blockIdx.y << 3) + (blockIdx.z << 8);
  const int xcd = hw & 7, sq = hw >> 3;
  const int pan = sq % 12, xb = sq / 12;
  const int p = pan * 8 + xcd;
  const int zz = p >> 5, py = p & 31;

  const float* Af = zz == 0 ? Aq : zz == 1 ? Akk : Av;
  const u16* Wb = zz == 0 ? Bq : zz == 1 ? Bk : Bv;
  const float* bias = zz == 0 ? cq : zz == 1 ? ck : cv;

  const int t = threadIdx.x;
  const int lane = t & 63;
  const int wv = t >> 6;
  const int wm = wv >> 1, wn = wv & 1;
  const int g = lane >> 4, lr = lane & 15;
  const int bm = py << 7, bn = xb << 7;
  const int K = DMODEL;

  float4 ax[4], ay[4];
  auto ALOAD = [&](int kt) {
    const int k0 = kt << 6;
#pragma unroll
    for (int i = 0; i < 4; ++i) {
      int c = t + (i << 8);
      int row = c >> 3, col8 = c & 7;
      const float* src = &Af[(size_t)(bm + row) * K + k0 + col8 * 8];
      ax[i] = *(const float4*)src;
      ay[i] = *(const float4*)(src + 4);
    }
  };
  auto AWRITE = [&]() {
#pragma unroll
    for (int i = 0; i < 4; ++i) {
      int c = t + (i << 8);
      int row = c >> 3, col8 = c & 7;
      *(short8*)&As[SWZ(row, col8)] = pack8(ax[i], ay[i]);
    }
  };
  auto BSTAGE = [&](u16* buf, int kt) {
    const int k0 = kt << 6;
#pragma unroll
    for (int i = 0; i < 4; ++i) {
      int c = t + (i << 8);
      int row = c >> 3, col8 = c & 7;
      int c8s = col8 ^ (row & 7);
      gl2lds16(&Wb[(size_t)(bn + row) * K + k0 + c8s * 8], &buf[c * 8]);
    }
  };

  f32x4 acc[4][4] = {};
  ALOAD(0);
  BSTAGE(Bs0, 0);
  AWRITE();
  __syncthreads();
  for (int kt = 0; kt < 16; ++kt) {
    u16* Bcur = (kt & 1) ? Bs1 : Bs0;
    u16* Bnxt = (kt & 1) ? Bs0 : Bs1;
    const bool more = (kt + 1 < 16);
    if (more) { ALOAD(kt + 1); BSTAGE(Bnxt, kt + 1); }
    bf16x8 af[2][4], bf[2][4];
#pragma unroll
    for (int kc = 0; kc < 2; ++kc)
#pragma unroll
      for (int f = 0; f < 4; ++f) {
        af[kc][f] = *(const bf16x8*)&As[SWZ(wm * 64 + f * 16 + lr, kc * 4 + g)];
        bf[kc][f] = *(const bf16x8*)&Bcur[SWZ(wn * 64 + f * 16 + lr, kc * 4 + g)];
      }
#pragma unroll
    for (int kc = 0; kc < 2; ++kc)
#pragma unroll
      for (int fm = 0; fm < 4; ++fm)
#pragma unroll
        for (int fn = 0; fn < 4; ++fn)
          acc[fm][fn] = mfma16x16(af[kc][fm], bf[kc][fn], acc[fm][fn]);
    __syncthreads();
    if (more) {
      AWRITE();
      __syncthreads();
    }
  }

  if (zz == 2) {
    u16* TL = SM;
    const int b = bm >> 11, s0 = bm & (S_LEN - 1), h0 = bn >> 6;
#pragma unroll
    for (int hh = 0; hh < 2; ++hh) {
      __syncthreads();
      if (wn == hh) {
#pragma unroll
        for (int fm = 0; fm < 4; ++fm)
#pragma unroll
          for (int fn = 0; fn < 4; ++fn) {
            const int lch = fn * 16 + lr;
            const float bb = bias[bn + hh * 64 + lch];
#pragma unroll
            for (int r = 0; r < 4; ++r)
              TL[lch * 132 + wm * 64 + fm * 16 + g * 4 + r] = f2bf(acc[fm][fn][r] + bb);
          }
      }
      __syncthreads();
#pragma unroll
      for (int i = 0; i < 4; ++i) {
        int c = t + (i << 8);
        int dk = c >> 4, sc = (c & 15) << 3;
        short8 vv = *(const short8*)&TL[dk * 132 + sc];
        *(short8*)&Ov[(((size_t)(b * NHEAD + h0 + hh)) * DKH + dk) * S_LEN + s0 + sc] = vv;
      }
    }
  } else {
    u16* Out = zz == 0 ? Oq : Ok;
#pragma unroll
    for (int fm = 0; fm < 4; ++fm)
#pragma unroll
      for (int fn = 0; fn < 4; ++fn) {
        const int col = bn + wn * 64 + fn * 16 + lr;
        const int h = col >> 6, dk = col & (DKH - 1);
        const float bb = bias[col];
#pragma unroll
        for (int r = 0; r < 4; ++r) {
          const int row = bm + wm * 64 + fm * 16 + g * 4 + r;
          const int b = row >> 11, s = row & (S_LEN - 1);
          Out[(((size_t)(b * NHEAD + h)) * S_LEN + s) * DKH + dk] = f2bf(acc[fm][fn][r] + bb);
        }
      }
  }
}

// ---------- O-projection: Ao(head-split bf16) @ Wo^T + bo -> f32 out ----------
__global__ __launch_bounds__(256)
void out_gemm(const u16* __restrict__ Ao, const u16* __restrict__ Wb,
              const float* __restrict__ bias, float* __restrict__ Out)
{
  __shared__ u16 SM[4 * 8192];
  const int hw = blockIdx.x + (blockIdx.y << 3);
  const int xcd = hw & 7, sq = hw >> 3;
  const int pan = sq & 3, xb = sq >> 2;
  const int prow = pan * 8 + xcd;

  const int t = threadIdx.x;
  const int lane = t & 63;
  const int wv = t >> 6;
  const int wm = wv >> 1, wn = wv & 1;
  const int g = lane >> 4, lr = lane & 15;
  const int bm = prow << 7, bn = xb << 7;
  const int K = DMODEL;

  auto STAGE = [&](int buf, int kt) {
    const int k0 = kt << 6;
    u16* Asb = SM + buf * 8192;
    u16* Bsb = SM + 16384 + buf * 8192;
#pragma unroll
    for (int i = 0; i < 4; ++i) {
      int c = t + (i << 8);
      int row = c >> 3, col8 = c & 7;
      int c8s = col8 ^ (row & 7);
      int grow = bm + row;
      int b = grow >> 11, s = grow & (S_LEN - 1);
      int k = k0 + c8s * 8;
      int h = k >> 6, dk = k & (DKH - 1);
      gl2lds16(&Ao[(((size_t)(b * NHEAD + h)) * S_LEN + s) * DKH + dk], &Asb[c * 8]);
      gl2lds16(&Wb[(size_t)(bn + row) * K + k0 + c8s * 8], &Bsb[c * 8]);
    }
  };

  f32x4 acc[4][4] = {};
  STAGE(0, 0);
  __syncthreads();
  for (int kt = 0; kt < 16; ++kt) {
    const int cur = kt & 1;
    if (kt + 1 < 16) STAGE(cur ^ 1, kt + 1);
    u16* Asb = SM + cur * 8192;
    u16* Bsb = SM + 16384 + cur * 8192;
    bf16x8 af[2][4], bf[2][4];
#pragma unroll
    for (int kc = 0; kc < 2; ++kc)
#pragma unroll
      for (int f = 0; f < 4; ++f) {
        af[kc][f] = *(const bf16x8*)&Asb[SWZ(wm * 64 + f * 16 + lr, kc * 4 + g)];
        bf[kc][f] = *(const bf16x8*)&Bsb[SWZ(wn * 64 + f * 16 + lr, kc * 4 + g)];
      }
#pragma unroll
    for (int kc = 0; kc < 2; ++kc)
#pragma unroll
      for (int fm = 0; fm < 4; ++fm)
#pragma unroll
        for (int fn = 0; fn < 4; ++fn)
          acc[fm][fn] = mfma16x16(af[kc][fm], bf[kc][fn], acc[fm][fn]);
    __syncthreads();
  }
#pragma unroll
  for (int fm = 0; fm < 4; ++fm)
#pragma unroll
    for (int fn = 0; fn < 4; ++fn) {
      const int col = bn + wn * 64 + fn * 16 + lr;
      const float bb = bias[col];
#pragma unroll
      for (int r = 0; r < 4; ++r) {
        const int row = bm + wm * 64 + fm * 16 + g * 4 + r;
        Out[(size_t)row * DMODEL + col] = acc[fm][fn][r] + bb;
      }
    }
}

// Flash attention, causal, paired q-tiles {p, 31-p}, head-split Ao.
// Swapped QK^T: S[kv][q]; scalar m,l; defer-rescale.
__global__ __launch_bounds__(256)
void attn_fwd(const u16* __restrict__ Qh, const u16* __restrict__ Kh,
              const u16* __restrict__ Vtg, u16* __restrict__ Ao)
{
  __shared__ u16 Ks[2][64 * LDT];
  __shared__ u16 Vs[2][64 * LDT];
  __shared__ u16 Ps[8][16 * LDT];
  const int t = threadIdx.x, lane = t & 63, w = t >> 6;
  const int g = lane >> 4, lr = lane & 15;
  const int bh = blockIdx.y;
  const int pA = blockIdx.x;
  const int tA = pA, tB = 31 - pA;
  const u16* Qb = Qh + (size_t)bh * S_LEN * DKH;
  const u16* Kb = Kh + (size_t)bh * S_LEN * DKH;
  const u16* Vb = Vtg + (size_t)bh * DKH * S_LEN;

  bf16x8 qfA[2], qfB[2];
#pragma unroll
  for (int kc = 0; kc < 2; ++kc) {
    qfA[kc] = *(const bf16x8*)&Qb[(size_t)(tA * 64 + w * 16 + lr) * DKH + kc * 32 + g * 8];
    qfB[kc] = *(const bf16x8*)&Qb[(size_t)(tB * 64 + w * 16 + lr) * DKH + kc * 32 + g * 8];
  }

  f32x4 oA[4] = {}, oB[4] = {};
  float mA = -1e30f, lA = 0.f, mB = -1e30f, lB = 0.f;

  const int r0 = t >> 3;
  const int c0 = (t & 7) << 3;
  short8 kr0, kr1, vr0, vr1;

  auto LOADT = [&](int kt) {
    const int kv0 = kt << 6;
    kr0 = *(const short8*)&Kb[(size_t)(kv0 + r0) * DKH + c0];
    kr1 = *(const short8*)&Kb[(size_t)(kv0 + r0 + 32) * DKH + c0];
    vr0 = *(const short8*)&Vb[(size_t)r0 * S_LEN + kv0 + c0];
    vr1 = *(const short8*)&Vb[(size_t)(r0 + 32) * S_LEN + kv0 + c0];
  };
  auto WRITET = [&](int b) {
    *(short8*)&Ks[b][r0 * LDT + c0] = kr0;
    *(short8*)&Ks[b][(r0 + 32) * LDT + c0] = kr1;
    *(short8*)&Vs[b][r0 * LDT + c0] = vr0;
    *(short8*)&Vs[b][(r0 + 32) * LDT + c0] = vr1;
  };

  auto COMPUTE = [&](int buf, const bf16x8* qf, f32x4* o, float& m, float& l,
                     int pslot, bool diag) {
    f32x4 sf[4];
#pragma unroll
    for (int fk = 0; fk < 4; ++fk) {
      f32x4 a = {};
#pragma unroll
      for (int kc = 0; kc < 2; ++kc) {
        bf16x8 kf = *(const bf16x8*)&Ks[buf][(fk * 16 + lr) * LDT + kc * 32 + g * 8];
        a = mfma16x16(kf, qf[kc], a);
      }
      sf[fk] = a;
    }
    if (diag) {
#pragma unroll
      for (int fk = 0; fk < 4; ++fk)
#pragma unroll
        for (int r = 0; r < 4; ++r)
          if (fk * 16 + 4 * g + r > w * 16 + lr) sf[fk][r] = -1e30f;
    }
    float pm = fmaxf(fmaxf(sf[0][0], sf[0][1]), fmaxf(sf[0][2], sf[0][3]));
#pragma unroll
    for (int fk = 1; fk < 4; ++fk)
      pm = fmaxf(pm, fmaxf(fmaxf(sf[fk][0], sf[fk][1]), fmaxf(sf[fk][2], sf[fk][3])));
    pm = fmaxf(pm, __shfl_xor(pm, 16, 64));
    pm = fmaxf(pm, __shfl_xor(pm, 32, 64));
    float alpha = 1.0f;
    if (!__all(pm - m <= 64.0f)) {
      float mn = fmaxf(m, pm);
      alpha = __expf((m - mn) * 0.125f);
      m = mn;
#pragma unroll
      for (int r = 0; r < 4; ++r) {
        float ar = __shfl(alpha, 4 * g + r, 64);
#pragma unroll
        for (int d = 0; d < 4; ++d) o[d][r] *= ar;
      }
    }
    float rs = 0.f;
#pragma unroll
    for (int fk = 0; fk < 4; ++fk) {
      float p0 = __expf((sf[fk][0] - m) * 0.125f);
      float p1 = __expf((sf[fk][1] - m) * 0.125f);
      float p2 = __expf((sf[fk][2] - m) * 0.125f);
      float p3 = __expf((sf[fk][3] - m) * 0.125f);
      rs += (p0 + p1) + (p2 + p3);
      short4v pk;
      pk[0] = (short)f2bf(p0); pk[1] = (short)f2bf(p1);
      pk[2] = (short)f2bf(p2); pk[3] = (short)f2bf(p3);
      *(short4v*)&Ps[pslot][lr * LDT + fk * 16 + 4 * g] = pk;
    }
    rs += __shfl_xor(rs, 16, 64);
    rs += __shfl_xor(rs, 32, 64);
    l = l * alpha + rs;
#pragma unroll
    for (int kc = 0; kc < 2; ++kc) {
      bf16x8 pf = *(const bf16x8*)&Ps[pslot][lr * LDT + kc * 32 + g * 8];
#pragma unroll
      for (int df = 0; df < 4; ++df) {
        bf16x8 vf = *(const bf16x8*)&Vs[buf][(df * 16 + lr) * LDT + kc * 32 + g * 8];
        o[df] = mfma16x16(pf, vf, o[df]);
      }
    }
  };

  const int nt = tB + 1;
  LOADT(0);
  WRITET(0);
  for (int kt = 0; kt < nt; ++kt) {
    const int cur = kt & 1;
    const bool more = (kt + 1 < nt);
    if (more) LOADT(kt + 1);
    __syncthreads();
    if (kt <= tA) COMPUTE(cur, qfA, oA, mA, lA, w, kt == tA);
    COMPUTE(cur, qfB, oB, mB, lB, 4 + w, kt == tB);
    if (more) WRITET(cur ^ 1);
  }

  float iA[4], iB[4];
#pragma unroll
  for (int r = 0; r < 4; ++r) {
    iA[r] = __builtin_amdgcn_rcpf(__shfl(lA, 4 * g + r, 64));
    iB[r] = __builtin_amdgcn_rcpf(__shfl(lB, 4 * g + r, 64));
  }
#pragma unroll
  for (int df = 0; df < 4; ++df)
#pragma unroll
    for (int r = 0; r < 4; ++r) {
      const int d = df * 16 + lr;
      const int qa = tA * 64 + w * 16 + g * 4 + r;
      const int qb2 = tB * 64 + w * 16 + g * 4 + r;
      Ao[((size_t)bh * S_LEN + qa) * DKH + d] = f2bf(oA[df][r] * iA[r]);
      Ao[((size_t)bh * S_LEN + qb2) * DKH + d] = f2bf(oB[df][r] * iB[r]);
    }
}

extern "C" void kernel_launch(void* const* d_in, const int* in_sizes, int n_in,
                              void* d_out, int out_size, void* d_ws, size_t ws_size,
                              hipStream_t stream)
{
  (void)in_sizes; (void)n_in; (void)out_size;
  const float* q  = (const float*)d_in[0];
  const float* k  = (const float*)d_in[1];
  const float* v  = (const float*)d_in[2];
  const float* Wq = (const float*)d_in[4];
  const float* bq = (const float*)d_in[5];
  const float* Wk = (const float*)d_in[6];
  const float* bk = (const float*)d_in[7];
  const float* Wv = (const float*)d_in[8];
  const float* bv = (const float*)d_in[9];
  const float* Wo = (const float*)d_in[10];
  const float* bo = (const float*)d_in[11];

  char* ws = (char*)d_ws;
  const size_t MB = 1024 * 1024;

  if (ws_size >= 56 * MB) {
    u16* Wqb = (u16*)(ws);               // 2 MB each
    u16* Wkb = (u16*)(ws + 2 * MB);
    u16* Wvb = (u16*)(ws + 4 * MB);
    u16* Wob = (u16*)(ws + 6 * MB);
    u16* qb  = (u16*)(ws + 8 * MB);      // 8 MB each (bf16 activations)
    u16* kb  = (u16*)(ws + 16 * MB);
    u16* vb  = (u16*)(ws + 24 * MB);
    u16* Qh  = (u16*)(ws + 32 * MB);
    u16* Kh  = (u16*)(ws + 40 * MB);
    u16* Vt  = (u16*)(ws + 48 * MB);
    u16* Ao  = qb;                       // qb dead after proj -> alias

    conv_bf16<<<dim3(2048, 7), 256, 0, stream>>>(Wq, Wk, Wv, Wo, q, k, v,
                                                 Wqb, Wkb, Wvb, Wob, qb, kb, vb);
    proj_gemm_bf16<<<dim3(8, 32, 3), 256, 0, stream>>>(qb, kb, vb, Wqb, Wkb, Wvb,
                                                       bq, bk, bv, Qh, Kh, Vt);
    attn_fwd<<<dim3(16, 2 * NHEAD), 256, 0, stream>>>(Qh, Kh, Vt, Ao);
    out_gemm<<<dim3(8, 32), 256, 0, stream>>>(Ao, Wob, bo, (float*)d_out);
  } else {
    // R8 fallback (40 MB scratch)
    u16* Wqb = (u16*)(ws);
    u16* Wkb = (u16*)(ws + 2 * MB);
    u16* Wvb = (u16*)(ws + 4 * MB);
    u16* Wob = (u16*)(ws + 6 * MB);
    u16* Qh  = (u16*)(ws + 8 * MB);
    u16* Kh  = (u16*)(ws + 16 * MB);
    u16* Vt  = (u16*)(ws + 24 * MB);
    u16* Ao  = (u16*)(ws + 32 * MB);

    conv_w<<<dim3(512, 4), 256, 0, stream>>>(Wq, Wk, Wv, Wo, Wqb, Wkb, Wvb, Wob);
    proj_gemm_f32<<<dim3(8, 32, 3), 256, 0, stream>>>(q, k, v, Wqb, Wkb, Wvb,
                                                      bq, bk, bv, Qh, Kh, Vt);
    attn_fwd<<<dim3(16, 2 * NHEAD), 256, 0, stream>>>(Qh, Kh, Vt, Ao);
    out_gemm<<<dim3(8, 32), 256, 0, stream>>>(Ao, Wob, bo, (float*)d_out);
  }
}